// Round 1
// baseline (2065.961 us; speedup 1.0000x reference)
//
#include <hip/hip_runtime.h>
#include <math.h>

constexpr int kT = 12;
constexpr int kD = 64;
constexpr int kH = 4;
constexpr int kDFF = 128;
constexpr float kNeg = 0.2f;
constexpr float kEps = 1e-5f;

__device__ __forceinline__ float wave_reduce_sum(float v) {
#pragma unroll
  for (int o = 32; o > 0; o >>= 1) v += __shfl_xor(v, o);
  return v;
}

// Per-node BN statistics folded into scale/shift: h = x*scale + shift
__global__ void bn_stats_kernel(const float* __restrict__ x, const float* __restrict__ g,
                                const float* __restrict__ b, float* __restrict__ scale,
                                float* __restrict__ shift, int N) {
  int n = blockIdx.x;
  const float* xr = x + (size_t)n * (kT * kD);
  float s = 0.f, s2 = 0.f;
  for (int i = threadIdx.x; i < kT * kD; i += blockDim.x) {
    float v = xr[i];
    s += v;
    s2 += v * v;
  }
  s = wave_reduce_sum(s);
  s2 = wave_reduce_sum(s2);
  __shared__ float ls[8], ls2[8];
  int wid = threadIdx.x >> 6, lane = threadIdx.x & 63;
  if (lane == 0) { ls[wid] = s; ls2[wid] = s2; }
  __syncthreads();
  if (threadIdx.x == 0) {
    float ts = 0.f, ts2 = 0.f;
    int nw = blockDim.x >> 6;
    for (int i = 0; i < nw; i++) { ts += ls[i]; ts2 += ls2[i]; }
    const float inv = 1.f / (kT * kD);
    float mean = ts * inv;
    float var = ts2 * inv - mean * mean;
    float sc = rsqrtf(var + kEps) * g[n];
    scale[n] = sc;
    shift[n] = b[n] - mean * sc;
  }
}

__global__ void deg_kernel(const int* __restrict__ dst, int* __restrict__ deg, int E) {
  int i = blockIdx.x * blockDim.x + threadIdx.x;
  if (i < E) atomicAdd(&deg[dst[i]], 1);
}

// single-block exclusive scan over N (chunks of 1024)
__global__ void scan_kernel(const int* __restrict__ deg, int* __restrict__ off, int N) {
  __shared__ int buf[1024];
  __shared__ int carry;
  int tid = threadIdx.x;
  if (tid == 0) { carry = 0; off[0] = 0; }
  __syncthreads();
  for (int base = 0; base < N; base += 1024) {
    int i = base + tid;
    int v = (i < N) ? deg[i] : 0;
    buf[tid] = v;
    __syncthreads();
    for (int s = 1; s < 1024; s <<= 1) {
      int t = (tid >= s) ? buf[tid - s] : 0;
      __syncthreads();
      buf[tid] += t;
      __syncthreads();
    }
    int incl = buf[tid] + carry;
    if (i < N) off[i + 1] = incl;
    __syncthreads();
    if (tid == 0) carry += buf[1023];
    __syncthreads();
  }
}

__global__ void fill_kernel(const int* __restrict__ dst, const int* __restrict__ off,
                            int* __restrict__ cursor, int* __restrict__ csr, int E) {
  int i = blockIdx.x * blockDim.x + threadIdx.x;
  if (i < E) {
    int d = dst[i];
    int p = atomicAdd(&cursor[d], 1);
    csr[off[d] + p] = i;
  }
}

// One wave per (n,t) row: h = x*sc+sh (registers), z = h@W (both relations),
// el/er via 16-lane group reduction.
__global__ void zel_kernel(const float* __restrict__ x, const float* __restrict__ scale,
                           const float* __restrict__ shift, const float* __restrict__ W1,
                           const float* __restrict__ al1, const float* __restrict__ ar1,
                           const float* __restrict__ W2, const float* __restrict__ al2,
                           const float* __restrict__ ar2, float* __restrict__ z1,
                           float* __restrict__ z2, float* __restrict__ el1,
                           float* __restrict__ er1, float* __restrict__ el2,
                           float* __restrict__ er2, int NT) {
  __shared__ float lh[4][64];
  int wid = threadIdx.x >> 6, lane = threadIdx.x & 63;
  int row = blockIdx.x * 4 + wid;
  if (row >= NT) return;
  int n = row / kT;
  float hv = x[(size_t)row * 64 + lane] * scale[n] + shift[n];
  lh[wid][lane] = hv;

  float z = 0.f;
#pragma unroll
  for (int d = 0; d < 64; d++) z = fmaf(lh[wid][d], W1[d * 64 + lane], z);
  z1[(size_t)row * 64 + lane] = z;
  float vl = z * al1[lane], vr = z * ar1[lane];
#pragma unroll
  for (int o = 8; o > 0; o >>= 1) { vl += __shfl_xor(vl, o); vr += __shfl_xor(vr, o); }
  if ((lane & 15) == 0) {
    el1[(size_t)row * 4 + (lane >> 4)] = vl;
    er1[(size_t)row * 4 + (lane >> 4)] = vr;
  }

  z = 0.f;
#pragma unroll
  for (int d = 0; d < 64; d++) z = fmaf(lh[wid][d], W2[d * 64 + lane], z);
  z2[(size_t)row * 64 + lane] = z;
  vl = z * al2[lane];
  vr = z * ar2[lane];
#pragma unroll
  for (int o = 8; o > 0; o >>= 1) { vl += __shfl_xor(vl, o); vr += __shfl_xor(vr, o); }
  if ((lane & 15) == 0) {
    el2[(size_t)row * 4 + (lane >> 4)] = vl;
    er2[(size_t)row * 4 + (lane >> 4)] = vr;
  }
}

__device__ __forceinline__ float gat_accum(int n, int t, int lane, int h,
                                           const int* __restrict__ src,
                                           const int* __restrict__ off,
                                           const int* __restrict__ csr,
                                           const float* __restrict__ el,
                                           const float* __restrict__ er,
                                           const float* __restrict__ z) {
  int b0 = off[n], b1 = off[n + 1];
  if (b1 <= b0) return 0.f;
  float er_h = er[(size_t)(n * kT + t) * 4 + h];
  float mh = -1e30f;
  for (int j = b0; j < b1; j++) {
    int s = src[csr[j]];
    float ev = el[(size_t)(s * kT + t) * 4 + h] + er_h;
    ev = ev < 0.f ? kNeg * ev : ev;
    mh = fmaxf(mh, ev);
  }
  float den = 0.f, accr = 0.f;
  for (int j = b0; j < b1; j++) {
    int s = src[csr[j]];
    float ev = el[(size_t)(s * kT + t) * 4 + h] + er_h;
    ev = ev < 0.f ? kNeg * ev : ev;
    float w = __expf(ev - mh);
    den += w;
    accr = fmaf(w, z[(size_t)(s * kT + t) * 64 + lane], accr);
  }
  return accr / fmaxf(den, 1e-16f);
}

// One wave per (n,t): gather-aggregate both relations via CSR, residual,
// write x2, and accumulate per-node BN2 sums (2 atomics per wave).
__global__ void agg_kernel(const float* __restrict__ x, const int* __restrict__ src1,
                           const int* __restrict__ off1, const int* __restrict__ csr1,
                           const float* __restrict__ el1, const float* __restrict__ er1,
                           const float* __restrict__ z1, const int* __restrict__ src2,
                           const int* __restrict__ off2, const int* __restrict__ csr2,
                           const float* __restrict__ el2, const float* __restrict__ er2,
                           const float* __restrict__ z2, float* __restrict__ x2,
                           float* __restrict__ bn2s, float* __restrict__ bn2q, int NT) {
  int wid = threadIdx.x >> 6, lane = threadIdx.x & 63;
  int row = blockIdx.x * 4 + wid;
  if (row >= NT) return;
  int n = row / kT;
  int t = row - n * kT;
  int h = lane >> 4;
  float acc = gat_accum(n, t, lane, h, src1, off1, csr1, el1, er1, z1) +
              gat_accum(n, t, lane, h, src2, off2, csr2, el2, er2, z2);
  float xv = x[(size_t)row * 64 + lane];
  float x2v = xv + acc;
  x2[(size_t)row * 64 + lane] = x2v;
  float s1 = wave_reduce_sum(x2v);
  float s2 = wave_reduce_sum(x2v * x2v);
  if (lane == 0) {
    atomicAdd(&bn2s[n], s1);
    atomicAdd(&bn2q[n], s2);
  }
}

__global__ void bn2fin_kernel(const float* __restrict__ s, const float* __restrict__ q,
                              const float* __restrict__ g, const float* __restrict__ b,
                              float* __restrict__ scale, float* __restrict__ shift, int N) {
  int n = blockIdx.x * blockDim.x + threadIdx.x;
  if (n < N) {
    const float inv = 1.f / (kT * kD);
    float mean = s[n] * inv;
    float var = q[n] * inv - mean * mean;
    float sc = rsqrtf(var + kEps) * g[n];
    scale[n] = sc;
    shift[n] = b[n] - mean * sc;
  }
}

// One wave per (n,t): BN2-normalize, 64->128 GELU -> 64, final residual.
__global__ void ff_kernel(const float* __restrict__ x2, const float* __restrict__ scale,
                          const float* __restrict__ shift, const float* __restrict__ w1,
                          const float* __restrict__ b1, const float* __restrict__ w2,
                          const float* __restrict__ b2, float* __restrict__ out, int NT) {
  __shared__ float lh[4][64];
  __shared__ float lg[4][128];
  int wid = threadIdx.x >> 6, lane = threadIdx.x & 63;
  int row = blockIdx.x * 4 + wid;
  if (row >= NT) return;
  int n = row / kT;
  float x2v = x2[(size_t)row * 64 + lane];
  float h2 = x2v * scale[n] + shift[n];
  lh[wid][lane] = h2;
  float u0 = b1[lane], u1 = b1[lane + 64];
#pragma unroll
  for (int d = 0; d < 64; d++) {
    float hv = lh[wid][d];
    u0 = fmaf(hv, w1[d * kDFF + lane], u0);
    u1 = fmaf(hv, w1[d * kDFF + lane + 64], u1);
  }
  u0 = 0.5f * u0 * (1.f + erff(u0 * 0.70710678118654752f));
  u1 = 0.5f * u1 * (1.f + erff(u1 * 0.70710678118654752f));
  lg[wid][lane] = u0;
  lg[wid][lane + 64] = u1;
  float o = b2[lane];
#pragma unroll
  for (int f = 0; f < kDFF; f++) o = fmaf(lg[wid][f], w2[f * 64 + lane], o);
  out[(size_t)row * 64 + lane] = x2v + o;
}

extern "C" void kernel_launch(void* const* d_in, const int* in_sizes, int n_in,
                              void* d_out, int out_size, void* d_ws, size_t ws_size,
                              hipStream_t stream) {
  const float* x = (const float*)d_in[0];
  const int* src1 = (const int*)d_in[1];
  const int* dst1 = (const int*)d_in[2];
  const int* src2 = (const int*)d_in[3];
  const int* dst2 = (const int*)d_in[4];
  const float* W1 = (const float*)d_in[5];
  const float* al1 = (const float*)d_in[6];
  const float* ar1 = (const float*)d_in[7];
  const float* W2 = (const float*)d_in[8];
  const float* al2 = (const float*)d_in[9];
  const float* ar2 = (const float*)d_in[10];
  const float* g1 = (const float*)d_in[11];
  const float* b1 = (const float*)d_in[12];
  const float* g2 = (const float*)d_in[13];
  const float* b2 = (const float*)d_in[14];
  const float* fw1 = (const float*)d_in[15];
  const float* fb1 = (const float*)d_in[16];
  const float* fw2 = (const float*)d_in[17];
  const float* fb2 = (const float*)d_in[18];

  const int N = in_sizes[11];  // bn1_g has shape (N,)
  const int E1 = in_sizes[1];
  const int E2 = in_sizes[3];
  const int NT = N * kT;

  char* p = (char*)d_ws;
  auto alloc = [&](size_t bytes) -> char* {
    char* r = p;
    p += (bytes + 255) & ~(size_t)255;
    return r;
  };
  float* z1 = (float*)alloc((size_t)NT * 64 * 4);
  float* z2 = (float*)alloc((size_t)NT * 64 * 4);
  float* el1 = (float*)alloc((size_t)NT * 4 * 4);
  float* er1 = (float*)alloc((size_t)NT * 4 * 4);
  float* el2 = (float*)alloc((size_t)NT * 4 * 4);
  float* er2 = (float*)alloc((size_t)NT * 4 * 4);
  float* x2 = (float*)alloc((size_t)NT * 64 * 4);
  float* sc1 = (float*)alloc((size_t)N * 4);
  float* sh1 = (float*)alloc((size_t)N * 4);
  float* sc2 = (float*)alloc((size_t)N * 4);
  float* sh2 = (float*)alloc((size_t)N * 4);
  int* off1 = (int*)alloc((size_t)(N + 1) * 4);
  int* off2 = (int*)alloc((size_t)(N + 1) * 4);
  int* csr1 = (int*)alloc((size_t)E1 * 4);
  int* csr2 = (int*)alloc((size_t)E2 * 4);
  // zero-init region (contiguous, one memset)
  char* zero_base = p;
  int* deg1 = (int*)alloc((size_t)N * 4);
  int* cur1 = (int*)alloc((size_t)N * 4);
  int* deg2 = (int*)alloc((size_t)N * 4);
  int* cur2 = (int*)alloc((size_t)N * 4);
  float* bn2s = (float*)alloc((size_t)N * 4);
  float* bn2q = (float*)alloc((size_t)N * 4);
  size_t zero_bytes = (size_t)(p - zero_base);
  hipMemsetAsync(zero_base, 0, zero_bytes, stream);

  bn_stats_kernel<<<N, 256, 0, stream>>>(x, g1, b1, sc1, sh1, N);
  deg_kernel<<<(E1 + 255) / 256, 256, 0, stream>>>(dst1, deg1, E1);
  deg_kernel<<<(E2 + 255) / 256, 256, 0, stream>>>(dst2, deg2, E2);
  scan_kernel<<<1, 1024, 0, stream>>>(deg1, off1, N);
  scan_kernel<<<1, 1024, 0, stream>>>(deg2, off2, N);
  fill_kernel<<<(E1 + 255) / 256, 256, 0, stream>>>(dst1, off1, cur1, csr1, E1);
  fill_kernel<<<(E2 + 255) / 256, 256, 0, stream>>>(dst2, off2, cur2, csr2, E2);
  zel_kernel<<<(NT + 3) / 4, 256, 0, stream>>>(x, sc1, sh1, W1, al1, ar1, W2, al2, ar2, z1,
                                               z2, el1, er1, el2, er2, NT);
  agg_kernel<<<(NT + 3) / 4, 256, 0, stream>>>(x, src1, off1, csr1, el1, er1, z1, src2, off2,
                                               csr2, el2, er2, z2, x2, bn2s, bn2q, NT);
  bn2fin_kernel<<<(N + 255) / 256, 256, 0, stream>>>(bn2s, bn2q, g2, b2, sc2, sh2, N);
  ff_kernel<<<(NT + 3) / 4, 256, 0, stream>>>(x2, sc2, sh2, fw1, fb1, fw2, fb2, (float*)d_out,
                                              NT);
}

// Round 2
// 775.445 us; speedup vs baseline: 2.6642x; 2.6642x over previous
//
#include <hip/hip_runtime.h>
#include <math.h>

constexpr int kT = 12;
constexpr float kNeg = 0.2f;
constexpr float kEps = 1e-5f;

__device__ __forceinline__ float rl(float v, int l) {
  return __uint_as_float(__builtin_amdgcn_readlane(__float_as_uint(v), l));
}

__device__ __forceinline__ float wave_reduce_sum(float v) {
#pragma unroll
  for (int o = 32; o > 0; o >>= 1) v += __shfl_xor(v, o);
  return v;
}

// Per-node BN statistics folded into scale/shift: h = x*scale + shift
__global__ void bn_stats_kernel(const float* __restrict__ x, const float* __restrict__ g,
                                const float* __restrict__ b, float* __restrict__ scale,
                                float* __restrict__ shift, int N) {
  int n = blockIdx.x;
  const float* xr = x + (size_t)n * (kT * 64);
  float s = 0.f, s2 = 0.f;
  for (int i = threadIdx.x; i < kT * 64; i += blockDim.x) {
    float v = xr[i];
    s += v;
    s2 += v * v;
  }
  s = wave_reduce_sum(s);
  s2 = wave_reduce_sum(s2);
  __shared__ float ls[4], ls2[4];
  int wid = threadIdx.x >> 6, lane = threadIdx.x & 63;
  if (lane == 0) { ls[wid] = s; ls2[wid] = s2; }
  __syncthreads();
  if (threadIdx.x == 0) {
    float ts = 0.f, ts2 = 0.f;
    for (int i = 0; i < 4; i++) { ts += ls[i]; ts2 += ls2[i]; }
    const float inv = 1.f / (kT * 64);
    float mean = ts * inv;
    float var = ts2 * inv - mean * mean;
    float sc = rsqrtf(var + kEps) * g[n];
    scale[n] = sc;
    shift[n] = b[n] - mean * sc;
  }
}

__global__ void deg_kernel(const int* __restrict__ dst, int* __restrict__ deg, int E) {
  int i = blockIdx.x * blockDim.x + threadIdx.x;
  if (i < E) atomicAdd(&deg[dst[i]], 1);
}

// single-block scan via shfl wave-scans (2 barriers per 1024-chunk)
__global__ void scan_kernel(const int* __restrict__ deg, int* __restrict__ off, int N) {
  __shared__ int wsum[16];
  __shared__ int carry;
  int tid = threadIdx.x, lane = tid & 63, wv = tid >> 6;
  if (tid == 0) { carry = 0; off[0] = 0; }
  __syncthreads();
  for (int base = 0; base < N; base += 1024) {
    int i = base + tid;
    int incl = (i < N) ? deg[i] : 0;
#pragma unroll
    for (int o = 1; o < 64; o <<= 1) {
      int y = __shfl_up(incl, o);
      if (lane >= o) incl += y;
    }
    if (lane == 63) wsum[wv] = incl;
    __syncthreads();
    if (tid < 16) {
      int p = wsum[tid];
#pragma unroll
      for (int o = 1; o < 16; o <<= 1) {
        int y = __shfl_up(p, o);
        if (tid >= o) p += y;
      }
      wsum[tid] = p;
    }
    __syncthreads();
    int prefix = carry + (wv > 0 ? wsum[wv - 1] : 0);
    if (i < N) off[i + 1] = prefix + incl;
    int total = carry + wsum[15];
    __syncthreads();
    if (tid == 0) carry = total;
    __syncthreads();
  }
}

// CSR fill: store SOURCE NODE id directly in csr slot order (kills one indirection)
__global__ void fill_kernel(const int* __restrict__ src, const int* __restrict__ dst,
                            const int* __restrict__ off, int* __restrict__ cursor,
                            int* __restrict__ scsr, int E) {
  int i = blockIdx.x * blockDim.x + threadIdx.x;
  if (i < E) {
    int d = dst[i];
    int p = atomicAdd(&cursor[d], 1);
    scsr[off[d] + p] = src[i];
  }
}

// Grid-stride, weights staged in LDS (32 KB), 2 rows per wave, h broadcast via readlane.
__global__ __launch_bounds__(256) void zel_kernel(
    const float* __restrict__ x, const float* __restrict__ scale,
    const float* __restrict__ shift, const float* __restrict__ W1,
    const float* __restrict__ al1, const float* __restrict__ ar1,
    const float* __restrict__ W2, const float* __restrict__ al2,
    const float* __restrict__ ar2, float* __restrict__ z1, float* __restrict__ z2,
    float* __restrict__ el1, float* __restrict__ er1, float* __restrict__ el2,
    float* __restrict__ er2, int NT) {
  __shared__ float sW1[4096];
  __shared__ float sW2[4096];
  for (int i = threadIdx.x; i < 4096; i += 256) { sW1[i] = W1[i]; sW2[i] = W2[i]; }
  __syncthreads();
  int lane = threadIdx.x & 63, wid = threadIdx.x >> 6;
  float al1v = al1[lane], ar1v = ar1[lane], al2v = al2[lane], ar2v = ar2[lane];
  int ngrp = (NT + 1) / 2;
  for (int grp = blockIdx.x * 4 + wid; grp < ngrp; grp += gridDim.x * 4) {
    int r0 = 2 * grp;
    int r1c = (r0 + 1 < NT) ? r0 + 1 : r0;
    bool v1 = r0 + 1 < NT;
    int n0 = r0 / kT, n1 = r1c / kT;
    float h0 = x[(size_t)r0 * 64 + lane] * scale[n0] + shift[n0];
    float h1 = x[(size_t)r1c * 64 + lane] * scale[n1] + shift[n1];
    int h = lane >> 4;

    // relation 1
    float a0 = 0.f, a1 = 0.f;
#pragma unroll
    for (int d = 0; d < 64; d++) {
      float w = sW1[d * 64 + lane];
      a0 = fmaf(rl(h0, d), w, a0);
      a1 = fmaf(rl(h1, d), w, a1);
    }
    z1[(size_t)r0 * 64 + lane] = a0;
    if (v1) z1[(size_t)r1c * 64 + lane] = a1;
    float vl0 = a0 * al1v, vr0 = a0 * ar1v, vl1 = a1 * al1v, vr1 = a1 * ar1v;
#pragma unroll
    for (int o = 1; o < 16; o <<= 1) {
      vl0 += __shfl_xor(vl0, o); vr0 += __shfl_xor(vr0, o);
      vl1 += __shfl_xor(vl1, o); vr1 += __shfl_xor(vr1, o);
    }
    if ((lane & 15) == 0) {
      el1[(size_t)r0 * 4 + h] = vl0; er1[(size_t)r0 * 4 + h] = vr0;
      if (v1) { el1[(size_t)r1c * 4 + h] = vl1; er1[(size_t)r1c * 4 + h] = vr1; }
    }

    // relation 2
    a0 = 0.f; a1 = 0.f;
#pragma unroll
    for (int d = 0; d < 64; d++) {
      float w = sW2[d * 64 + lane];
      a0 = fmaf(rl(h0, d), w, a0);
      a1 = fmaf(rl(h1, d), w, a1);
    }
    z2[(size_t)r0 * 64 + lane] = a0;
    if (v1) z2[(size_t)r1c * 64 + lane] = a1;
    vl0 = a0 * al2v; vr0 = a0 * ar2v; vl1 = a1 * al2v; vr1 = a1 * ar2v;
#pragma unroll
    for (int o = 1; o < 16; o <<= 1) {
      vl0 += __shfl_xor(vl0, o); vr0 += __shfl_xor(vr0, o);
      vl1 += __shfl_xor(vl1, o); vr1 += __shfl_xor(vr1, o);
    }
    if ((lane & 15) == 0) {
      el2[(size_t)r0 * 4 + h] = vl0; er2[(size_t)r0 * 4 + h] = vr0;
      if (v1) { el2[(size_t)r1c * 4 + h] = vl1; er2[(size_t)r1c * 4 + h] = vr1; }
    }
  }
}

// Single-pass softmax (no max subtraction: inputs are BN-normalized, |e| small,
// exp(e) is safe in fp32 and alpha is mathematically identical).
__device__ __forceinline__ float gat_rel(int n, int t, int lane, int h,
                                         const int* __restrict__ scsr,
                                         const int* __restrict__ off,
                                         const float* __restrict__ el,
                                         const float* __restrict__ er,
                                         const float* __restrict__ z) {
  int b0 = off[n], b1 = off[n + 1];
  if (b1 <= b0) return 0.f;
  float er_h = er[(size_t)(n * kT + t) * 4 + h];
  float num = 0.f, den = 0.f;
  int s_next = scsr[b0];
#pragma unroll 2
  for (int j = b0; j < b1; j++) {
    int s = s_next;
    if (j + 1 < b1) s_next = scsr[j + 1];
    int srow = s * kT + t;
    float ev = el[(size_t)srow * 4 + h] + er_h;
    ev = ev < 0.f ? kNeg * ev : ev;
    float w = __expf(ev);
    den += w;
    num = fmaf(w, z[(size_t)srow * 64 + lane], num);
  }
  return num / den;
}

__global__ void agg_kernel(const float* __restrict__ x, const int* __restrict__ scsr1,
                           const int* __restrict__ off1, const float* __restrict__ el1,
                           const float* __restrict__ er1, const float* __restrict__ z1,
                           const int* __restrict__ scsr2, const int* __restrict__ off2,
                           const float* __restrict__ el2, const float* __restrict__ er2,
                           const float* __restrict__ z2, float* __restrict__ x2,
                           float* __restrict__ bn2s, float* __restrict__ bn2q, int NT) {
  int wid = threadIdx.x >> 6, lane = threadIdx.x & 63;
  int row = blockIdx.x * 4 + wid;
  if (row >= NT) return;
  int n = row / kT;
  int t = row - n * kT;
  int h = lane >> 4;
  float acc = gat_rel(n, t, lane, h, scsr1, off1, el1, er1, z1) +
              gat_rel(n, t, lane, h, scsr2, off2, el2, er2, z2);
  float xv = x[(size_t)row * 64 + lane];
  float x2v = xv + acc;
  x2[(size_t)row * 64 + lane] = x2v;
  float s1 = wave_reduce_sum(x2v);
  float s2 = wave_reduce_sum(x2v * x2v);
  if (lane == 0) {
    atomicAdd(&bn2s[n], s1);
    atomicAdd(&bn2q[n], s2);
  }
}

__global__ void bn2fin_kernel(const float* __restrict__ s, const float* __restrict__ q,
                              const float* __restrict__ g, const float* __restrict__ b,
                              float* __restrict__ scale, float* __restrict__ shift, int N) {
  int n = blockIdx.x * blockDim.x + threadIdx.x;
  if (n < N) {
    const float inv = 1.f / (kT * 64);
    float mean = s[n] * inv;
    float var = q[n] * inv - mean * mean;
    float sc = rsqrtf(var + kEps) * g[n];
    scale[n] = sc;
    shift[n] = b[n] - mean * sc;
  }
}

// Grid-stride FF: weights staged in LDS (64 KB), 4 rows per wave,
// h/g broadcast via readlane. Lane computes outputs {2*lane, 2*lane+1} of the
// 128-wide hidden layer, then output {lane} of the 64-wide projection.
__global__ __launch_bounds__(256) void ff_kernel(
    const float* __restrict__ x2, const float* __restrict__ scale,
    const float* __restrict__ shift, const float* __restrict__ w1,
    const float* __restrict__ b1, const float* __restrict__ w2,
    const float* __restrict__ b2, float* __restrict__ out, int NT) {
  __shared__ float sw1[64 * 128];
  __shared__ float sw2[128 * 64];
  for (int i = threadIdx.x; i < 64 * 128; i += 256) { sw1[i] = w1[i]; sw2[i] = w2[i]; }
  __syncthreads();
  int lane = threadIdx.x & 63, wid = threadIdx.x >> 6;
  float2 bb = *(const float2*)&b1[2 * lane];
  float b2v = b2[lane];
  int ngrp = (NT + 3) / 4;
  for (int grp = blockIdx.x * 4 + wid; grp < ngrp; grp += gridDim.x * 4) {
    int r0 = 4 * grp;
    float h[4], xr[4];
#pragma unroll
    for (int r = 0; r < 4; r++) {
      int row = r0 + r;
      int rc = (row < NT) ? row : NT - 1;
      int n = rc / kT;
      float xv = x2[(size_t)rc * 64 + lane];
      xr[r] = xv;
      h[r] = xv * scale[n] + shift[n];
    }
    float u[4][2];
#pragma unroll
    for (int r = 0; r < 4; r++) { u[r][0] = bb.x; u[r][1] = bb.y; }
#pragma unroll
    for (int d = 0; d < 64; d++) {
      float2 w = *(const float2*)&sw1[d * 128 + 2 * lane];
#pragma unroll
      for (int r = 0; r < 4; r++) {
        float hd = rl(h[r], d);
        u[r][0] = fmaf(hd, w.x, u[r][0]);
        u[r][1] = fmaf(hd, w.y, u[r][1]);
      }
    }
#pragma unroll
    for (int r = 0; r < 4; r++) {
      u[r][0] = 0.5f * u[r][0] * (1.f + erff(u[r][0] * 0.70710678118654752f));
      u[r][1] = 0.5f * u[r][1] * (1.f + erff(u[r][1] * 0.70710678118654752f));
    }
    float o_[4];
#pragma unroll
    for (int r = 0; r < 4; r++) o_[r] = b2v;
#pragma unroll
    for (int f = 0; f < 128; f++) {
      float wv = sw2[f * 64 + lane];
#pragma unroll
      for (int r = 0; r < 4; r++) {
        float gf = rl(u[r][f & 1], f >> 1);
        o_[r] = fmaf(gf, wv, o_[r]);
      }
    }
#pragma unroll
    for (int r = 0; r < 4; r++) {
      int row = r0 + r;
      if (row < NT) out[(size_t)row * 64 + lane] = xr[r] + o_[r];
    }
  }
}

extern "C" void kernel_launch(void* const* d_in, const int* in_sizes, int n_in,
                              void* d_out, int out_size, void* d_ws, size_t ws_size,
                              hipStream_t stream) {
  const float* x = (const float*)d_in[0];
  const int* src1 = (const int*)d_in[1];
  const int* dst1 = (const int*)d_in[2];
  const int* src2 = (const int*)d_in[3];
  const int* dst2 = (const int*)d_in[4];
  const float* W1 = (const float*)d_in[5];
  const float* al1 = (const float*)d_in[6];
  const float* ar1 = (const float*)d_in[7];
  const float* W2 = (const float*)d_in[8];
  const float* al2 = (const float*)d_in[9];
  const float* ar2 = (const float*)d_in[10];
  const float* g1 = (const float*)d_in[11];
  const float* b1 = (const float*)d_in[12];
  const float* g2 = (const float*)d_in[13];
  const float* b2 = (const float*)d_in[14];
  const float* fw1 = (const float*)d_in[15];
  const float* fb1 = (const float*)d_in[16];
  const float* fw2 = (const float*)d_in[17];
  const float* fb2 = (const float*)d_in[18];

  const int N = in_sizes[11];
  const int E1 = in_sizes[1];
  const int E2 = in_sizes[3];
  const int NT = N * kT;

  char* p = (char*)d_ws;
  auto alloc = [&](size_t bytes) -> char* {
    char* r = p;
    p += (bytes + 255) & ~(size_t)255;
    return r;
  };
  float* z1 = (float*)alloc((size_t)NT * 64 * 4);
  float* z2 = (float*)alloc((size_t)NT * 64 * 4);
  float* el1 = (float*)alloc((size_t)NT * 4 * 4);
  float* er1 = (float*)alloc((size_t)NT * 4 * 4);
  float* el2 = (float*)alloc((size_t)NT * 4 * 4);
  float* er2 = (float*)alloc((size_t)NT * 4 * 4);
  float* x2 = (float*)alloc((size_t)NT * 64 * 4);
  float* sc1 = (float*)alloc((size_t)N * 4);
  float* sh1 = (float*)alloc((size_t)N * 4);
  float* sc2 = (float*)alloc((size_t)N * 4);
  float* sh2 = (float*)alloc((size_t)N * 4);
  int* off1 = (int*)alloc((size_t)(N + 1) * 4);
  int* off2 = (int*)alloc((size_t)(N + 1) * 4);
  int* scsr1 = (int*)alloc((size_t)E1 * 4);
  int* scsr2 = (int*)alloc((size_t)E2 * 4);
  char* zero_base = p;
  int* deg1 = (int*)alloc((size_t)N * 4);
  int* cur1 = (int*)alloc((size_t)N * 4);
  int* deg2 = (int*)alloc((size_t)N * 4);
  int* cur2 = (int*)alloc((size_t)N * 4);
  float* bn2s = (float*)alloc((size_t)N * 4);
  float* bn2q = (float*)alloc((size_t)N * 4);
  size_t zero_bytes = (size_t)(p - zero_base);
  hipMemsetAsync(zero_base, 0, zero_bytes, stream);

  bn_stats_kernel<<<N, 256, 0, stream>>>(x, g1, b1, sc1, sh1, N);
  deg_kernel<<<(E1 + 255) / 256, 256, 0, stream>>>(dst1, deg1, E1);
  deg_kernel<<<(E2 + 255) / 256, 256, 0, stream>>>(dst2, deg2, E2);
  scan_kernel<<<1, 1024, 0, stream>>>(deg1, off1, N);
  scan_kernel<<<1, 1024, 0, stream>>>(deg2, off2, N);
  fill_kernel<<<(E1 + 255) / 256, 256, 0, stream>>>(src1, dst1, off1, cur1, scsr1, E1);
  fill_kernel<<<(E2 + 255) / 256, 256, 0, stream>>>(src2, dst2, off2, cur2, scsr2, E2);
  zel_kernel<<<1280, 256, 0, stream>>>(x, sc1, sh1, W1, al1, ar1, W2, al2, ar2, z1, z2, el1,
                                       er1, el2, er2, NT);
  agg_kernel<<<(NT + 3) / 4, 256, 0, stream>>>(x, scsr1, off1, el1, er1, z1, scsr2, off2, el2,
                                               er2, z2, x2, bn2s, bn2q, NT);
  bn2fin_kernel<<<(N + 255) / 256, 256, 0, stream>>>(bn2s, bn2q, g2, b2, sc2, sh2, N);
  ff_kernel<<<512, 256, 0, stream>>>(x2, sc2, sh2, fw1, fb1, fw2, fb2, (float*)d_out, NT);
}

// Round 3
// 452.916 us; speedup vs baseline: 4.5615x; 1.7121x over previous
//
#include <hip/hip_runtime.h>
#include <math.h>

constexpr int kT = 12;
constexpr float kNeg = 0.2f;
constexpr float kEps = 1e-5f;

typedef __attribute__((ext_vector_type(8))) short bf16x8;
typedef __attribute__((ext_vector_type(4))) float f32x4;

__device__ __forceinline__ float rl(float v, int l) {
  return __uint_as_float(__builtin_amdgcn_readlane(__float_as_uint(v), l));
}

__device__ __forceinline__ short f2bf(float f) {
  union { float f; unsigned u; } v;
  v.f = f;
  unsigned r = (v.u + 0x7fffu + ((v.u >> 16) & 1u)) >> 16;
  return (short)r;
}

__device__ __forceinline__ float wave_reduce_sum(float v) {
#pragma unroll
  for (int o = 32; o > 0; o >>= 1) v += __shfl_xor(v, o);
  return v;
}

// Per-node BN statistics folded into scale/shift: h = x*scale + shift
__global__ void bn_stats_kernel(const float* __restrict__ x, const float* __restrict__ g,
                                const float* __restrict__ b, float* __restrict__ scale,
                                float* __restrict__ shift, int N) {
  int n = blockIdx.x;
  const float* xr = x + (size_t)n * (kT * 64);
  float s = 0.f, s2 = 0.f;
  for (int i = threadIdx.x; i < kT * 64; i += blockDim.x) {
    float v = xr[i];
    s += v;
    s2 += v * v;
  }
  s = wave_reduce_sum(s);
  s2 = wave_reduce_sum(s2);
  __shared__ float ls[4], ls2[4];
  int wid = threadIdx.x >> 6, lane = threadIdx.x & 63;
  if (lane == 0) { ls[wid] = s; ls2[wid] = s2; }
  __syncthreads();
  if (threadIdx.x == 0) {
    float ts = 0.f, ts2 = 0.f;
    for (int i = 0; i < 4; i++) { ts += ls[i]; ts2 += ls2[i]; }
    const float inv = 1.f / (kT * 64);
    float mean = ts * inv;
    float var = ts2 * inv - mean * mean;
    float sc = rsqrtf(var + kEps) * g[n];
    scale[n] = sc;
    shift[n] = b[n] - mean * sc;
  }
}

__global__ void deg_kernel(const int* __restrict__ dst, int* __restrict__ deg, int E) {
  int i = blockIdx.x * blockDim.x + threadIdx.x;
  if (i < E) atomicAdd(&deg[dst[i]], 1);
}

// single-block scan via shfl wave-scans (2 barriers per 1024-chunk)
__global__ void scan_kernel(const int* __restrict__ deg, int* __restrict__ off, int N) {
  __shared__ int wsum[16];
  __shared__ int carry;
  int tid = threadIdx.x, lane = tid & 63, wv = tid >> 6;
  if (tid == 0) { carry = 0; off[0] = 0; }
  __syncthreads();
  for (int base = 0; base < N; base += 1024) {
    int i = base + tid;
    int incl = (i < N) ? deg[i] : 0;
#pragma unroll
    for (int o = 1; o < 64; o <<= 1) {
      int y = __shfl_up(incl, o);
      if (lane >= o) incl += y;
    }
    if (lane == 63) wsum[wv] = incl;
    __syncthreads();
    if (tid < 16) {
      int p = wsum[tid];
#pragma unroll
      for (int o = 1; o < 16; o <<= 1) {
        int y = __shfl_up(p, o);
        if (tid >= o) p += y;
      }
      wsum[tid] = p;
    }
    __syncthreads();
    int prefix = carry + (wv > 0 ? wsum[wv - 1] : 0);
    if (i < N) off[i + 1] = prefix + incl;
    int total = carry + wsum[15];
    __syncthreads();
    if (tid == 0) carry = total;
    __syncthreads();
  }
}

// CSR fill: store SOURCE NODE id directly in csr slot order
__global__ void fill_kernel(const int* __restrict__ src, const int* __restrict__ dst,
                            const int* __restrict__ off, int* __restrict__ cursor,
                            int* __restrict__ scsr, int E) {
  int i = blockIdx.x * blockDim.x + threadIdx.x;
  if (i < E) {
    int d = dst[i];
    int p = atomicAdd(&cursor[d], 1);
    scsr[off[d] + p] = src[i];
  }
}

// Grid-stride, weights staged in LDS (32 KB), 2 rows per wave, h broadcast via readlane.
__global__ __launch_bounds__(256) void zel_kernel(
    const float* __restrict__ x, const float* __restrict__ scale,
    const float* __restrict__ shift, const float* __restrict__ W1,
    const float* __restrict__ al1, const float* __restrict__ ar1,
    const float* __restrict__ W2, const float* __restrict__ al2,
    const float* __restrict__ ar2, float* __restrict__ z1, float* __restrict__ z2,
    float* __restrict__ el1, float* __restrict__ er1, float* __restrict__ el2,
    float* __restrict__ er2, int NT) {
  __shared__ float sW1[4096];
  __shared__ float sW2[4096];
  for (int i = threadIdx.x; i < 4096; i += 256) { sW1[i] = W1[i]; sW2[i] = W2[i]; }
  __syncthreads();
  int lane = threadIdx.x & 63, wid = threadIdx.x >> 6;
  float al1v = al1[lane], ar1v = ar1[lane], al2v = al2[lane], ar2v = ar2[lane];
  int ngrp = (NT + 1) / 2;
  for (int grp = blockIdx.x * 4 + wid; grp < ngrp; grp += gridDim.x * 4) {
    int r0 = 2 * grp;
    int r1c = (r0 + 1 < NT) ? r0 + 1 : r0;
    bool v1 = r0 + 1 < NT;
    int n0 = r0 / kT, n1 = r1c / kT;
    float h0 = x[(size_t)r0 * 64 + lane] * scale[n0] + shift[n0];
    float h1 = x[(size_t)r1c * 64 + lane] * scale[n1] + shift[n1];
    int h = lane >> 4;

    float a0 = 0.f, a1 = 0.f;
#pragma unroll
    for (int d = 0; d < 64; d++) {
      float w = sW1[d * 64 + lane];
      a0 = fmaf(rl(h0, d), w, a0);
      a1 = fmaf(rl(h1, d), w, a1);
    }
    z1[(size_t)r0 * 64 + lane] = a0;
    if (v1) z1[(size_t)r1c * 64 + lane] = a1;
    float vl0 = a0 * al1v, vr0 = a0 * ar1v, vl1 = a1 * al1v, vr1 = a1 * ar1v;
#pragma unroll
    for (int o = 1; o < 16; o <<= 1) {
      vl0 += __shfl_xor(vl0, o); vr0 += __shfl_xor(vr0, o);
      vl1 += __shfl_xor(vl1, o); vr1 += __shfl_xor(vr1, o);
    }
    if ((lane & 15) == 0) {
      el1[(size_t)r0 * 4 + h] = vl0; er1[(size_t)r0 * 4 + h] = vr0;
      if (v1) { el1[(size_t)r1c * 4 + h] = vl1; er1[(size_t)r1c * 4 + h] = vr1; }
    }

    a0 = 0.f; a1 = 0.f;
#pragma unroll
    for (int d = 0; d < 64; d++) {
      float w = sW2[d * 64 + lane];
      a0 = fmaf(rl(h0, d), w, a0);
      a1 = fmaf(rl(h1, d), w, a1);
    }
    z2[(size_t)r0 * 64 + lane] = a0;
    if (v1) z2[(size_t)r1c * 64 + lane] = a1;
    vl0 = a0 * al2v; vr0 = a0 * ar2v; vl1 = a1 * al2v; vr1 = a1 * ar2v;
#pragma unroll
    for (int o = 1; o < 16; o <<= 1) {
      vl0 += __shfl_xor(vl0, o); vr0 += __shfl_xor(vr0, o);
      vl1 += __shfl_xor(vl1, o); vr1 += __shfl_xor(vr1, o);
    }
    if ((lane & 15) == 0) {
      el2[(size_t)r0 * 4 + h] = vl0; er2[(size_t)r0 * 4 + h] = vr0;
      if (v1) { el2[(size_t)r1c * 4 + h] = vl1; er2[(size_t)r1c * 4 + h] = vr1; }
    }
  }
}

// Single-pass softmax (no max subtraction: BN-normalized inputs, exp safe in fp32)
__device__ __forceinline__ float gat_rel(int n, int t, int lane, int h,
                                         const int* __restrict__ scsr,
                                         const int* __restrict__ off,
                                         const float* __restrict__ el,
                                         const float* __restrict__ er,
                                         const float* __restrict__ z) {
  int b0 = off[n], b1 = off[n + 1];
  if (b1 <= b0) return 0.f;
  float er_h = er[(size_t)(n * kT + t) * 4 + h];
  float num = 0.f, den = 0.f;
  int s_next = scsr[b0];
#pragma unroll 2
  for (int j = b0; j < b1; j++) {
    int s = s_next;
    if (j + 1 < b1) s_next = scsr[j + 1];
    int srow = s * kT + t;
    float ev = el[(size_t)srow * 4 + h] + er_h;
    ev = ev < 0.f ? kNeg * ev : ev;
    float w = __expf(ev);
    den += w;
    num = fmaf(w, z[(size_t)srow * 64 + lane], num);
  }
  return num / den;
}

__global__ void agg_kernel(const float* __restrict__ x, const int* __restrict__ scsr1,
                           const int* __restrict__ off1, const float* __restrict__ el1,
                           const float* __restrict__ er1, const float* __restrict__ z1,
                           const int* __restrict__ scsr2, const int* __restrict__ off2,
                           const float* __restrict__ el2, const float* __restrict__ er2,
                           const float* __restrict__ z2, float* __restrict__ x2,
                           float* __restrict__ bn2s, float* __restrict__ bn2q, int NT) {
  int wid = threadIdx.x >> 6, lane = threadIdx.x & 63;
  int row = blockIdx.x * 4 + wid;
  if (row >= NT) return;
  int n = row / kT;
  int t = row - n * kT;
  int h = lane >> 4;
  float acc = gat_rel(n, t, lane, h, scsr1, off1, el1, er1, z1) +
              gat_rel(n, t, lane, h, scsr2, off2, el2, er2, z2);
  float xv = x[(size_t)row * 64 + lane];
  float x2v = xv + acc;
  x2[(size_t)row * 64 + lane] = x2v;
  float s1 = wave_reduce_sum(x2v);
  float s2 = wave_reduce_sum(x2v * x2v);
  if (lane == 0) {
    atomicAdd(&bn2s[n], s1);
    atomicAdd(&bn2q[n], s2);
  }
}

__global__ void bn2fin_kernel(const float* __restrict__ s, const float* __restrict__ q,
                              const float* __restrict__ g, const float* __restrict__ b,
                              float* __restrict__ scale, float* __restrict__ shift, int N) {
  int n = blockIdx.x * blockDim.x + threadIdx.x;
  if (n < N) {
    const float inv = 1.f / (kT * 64);
    float mean = s[n] * inv;
    float var = q[n] * inv - mean * mean;
    float sc = rsqrtf(var + kEps) * g[n];
    scale[n] = sc;
    shift[n] = b[n] - mean * sc;
  }
}

// ---------------------------------------------------------------------------
// MFMA FF: 16 rows per wave-tile. Both GEMMs computed transposed:
//   hidden^T[128][16] = w1^T @ h^T   (8 m-tiles, K=64 in 2 chunks)
//   out^T   [64][16]  = w2^T @ hid^T (4 m-tiles, K=128 in 4 chunks)
// Weight fragments (MFMA A-layout, bf16) staged in LDS once per block.
// The C->B relayout between GEMMs is done in-register with __shfl.
// ---------------------------------------------------------------------------
__global__ __launch_bounds__(256) void ff_kernel(
    const float* __restrict__ x2, const float* __restrict__ scale,
    const float* __restrict__ shift, const float* __restrict__ w1,
    const float* __restrict__ b1, const float* __restrict__ w2,
    const float* __restrict__ b2, float* __restrict__ out, int NT) {
  __shared__ bf16x8 sW1[16][64];  // [mt*2+kc][lane] : w1^T A-frags, 16 KB
  __shared__ bf16x8 sW2[16][64];  // [mt2*4+kc2][lane] : w2^T A-frags, 16 KB
  int lane = threadIdx.x & 63, wid = threadIdx.x >> 6;
  int m = lane & 15, q = lane >> 4;

  for (int fi = wid; fi < 16; fi += 4) {
    int mt = fi >> 1, kc = fi & 1;
    bf16x8 v;
#pragma unroll
    for (int j = 0; j < 8; j++)
      v[j] = f2bf(w1[(kc * 32 + q * 8 + j) * 128 + mt * 16 + m]);
    sW1[fi][lane] = v;
    int mt2 = fi >> 2, kc2 = fi & 3;
    bf16x8 u;
#pragma unroll
    for (int j = 0; j < 8; j++)
      u[j] = f2bf(w2[(kc2 * 32 + q * 8 + j) * 64 + mt2 * 16 + m]);
    sW2[fi][lane] = u;
  }
  __syncthreads();

  // biases in lane-mapped registers (C-layout: feat = mt*16 + 4q + r)
  float bias1v[8][4], bias2v[4][4];
#pragma unroll
  for (int mt = 0; mt < 8; mt++)
#pragma unroll
    for (int r = 0; r < 4; r++) bias1v[mt][r] = b1[mt * 16 + 4 * q + r];
#pragma unroll
  for (int mt = 0; mt < 4; mt++)
#pragma unroll
    for (int r = 0; r < 4; r++) bias2v[mt][r] = b2[mt * 16 + 4 * q + r];

  int ntile = (NT + 15) / 16;
  for (int tile = blockIdx.x * 4 + wid; tile < ntile; tile += gridDim.x * 4) {
    int r0 = tile * 16;
    int row = r0 + m;
    int rowc = (row < NT) ? row : NT - 1;
    int n = rowc / kT;
    float sc = scale[n], sh = shift[n];

    // h fragments (B-operand of GEMM1): lane holds h[rowc][kc*32 + 8q + j]
    bf16x8 hf[2];
#pragma unroll
    for (int kc = 0; kc < 2; kc++) {
      const float4 p0 = *(const float4*)&x2[(size_t)rowc * 64 + kc * 32 + q * 8];
      const float4 p1 = *(const float4*)&x2[(size_t)rowc * 64 + kc * 32 + q * 8 + 4];
      hf[kc][0] = f2bf(fmaf(p0.x, sc, sh));
      hf[kc][1] = f2bf(fmaf(p0.y, sc, sh));
      hf[kc][2] = f2bf(fmaf(p0.z, sc, sh));
      hf[kc][3] = f2bf(fmaf(p0.w, sc, sh));
      hf[kc][4] = f2bf(fmaf(p1.x, sc, sh));
      hf[kc][5] = f2bf(fmaf(p1.y, sc, sh));
      hf[kc][6] = f2bf(fmaf(p1.z, sc, sh));
      hf[kc][7] = f2bf(fmaf(p1.w, sc, sh));
    }

    // GEMM1: hidden^T tiles
    f32x4 acc[8];
#pragma unroll
    for (int mt = 0; mt < 8; mt++) acc[mt] = (f32x4){0.f, 0.f, 0.f, 0.f};
#pragma unroll
    for (int kc = 0; kc < 2; kc++)
#pragma unroll
      for (int mt = 0; mt < 8; mt++)
        acc[mt] = __builtin_amdgcn_mfma_f32_16x16x32_bf16(sW1[mt * 2 + kc][lane], hf[kc],
                                                          acc[mt], 0, 0, 0);
    // bias + exact GELU; lane now holds hidden[m-row? no: hidden[dataRow=lane&15 ...]
    // C-layout: g[mt][r] = hidden[data_row = m][feat = mt*16 + 4q + r]
    float g[8][4];
#pragma unroll
    for (int mt = 0; mt < 8; mt++)
#pragma unroll
      for (int r = 0; r < 4; r++) {
        float u = acc[mt][r] + bias1v[mt][r];
        g[mt][r] = 0.5f * u * (1.f + erff(u * 0.70710678118654752f));
      }

    // relayout: build B-operand frags b2f[kc]: lane holds hidden[m][kc*32+8q+j]
    bf16x8 b2f[4];
#pragma unroll
    for (int kc = 0; kc < 4; kc++)
#pragma unroll
      for (int j = 0; j < 8; j++) {
        int srcq = (2 * q + (j >> 2)) & 3;
        int src = srcq * 16 + m;
        float v0 = __shfl(g[2 * kc][j & 3], src);
        float v1 = __shfl(g[2 * kc + 1][j & 3], src);
        b2f[kc][j] = f2bf((q >= 2) ? v1 : v0);
      }

    // GEMM2: out^T tiles
    f32x4 acc2[4];
#pragma unroll
    for (int mt = 0; mt < 4; mt++) acc2[mt] = (f32x4){0.f, 0.f, 0.f, 0.f};
#pragma unroll
    for (int kc = 0; kc < 4; kc++)
#pragma unroll
      for (int mt = 0; mt < 4; mt++)
        acc2[mt] = __builtin_amdgcn_mfma_f32_16x16x32_bf16(sW2[mt * 4 + kc][lane], b2f[kc],
                                                           acc2[mt], 0, 0, 0);

    // residual + store: lane owns row rowc, feats mt*16+4q+0..3 (float4)
    if (row < NT) {
#pragma unroll
      for (int mt = 0; mt < 4; mt++) {
        size_t base = (size_t)row * 64 + mt * 16 + 4 * q;
        float4 xr = *(const float4*)&x2[base];
        float4 o;
        o.x = acc2[mt][0] + bias2v[mt][0] + xr.x;
        o.y = acc2[mt][1] + bias2v[mt][1] + xr.y;
        o.z = acc2[mt][2] + bias2v[mt][2] + xr.z;
        o.w = acc2[mt][3] + bias2v[mt][3] + xr.w;
        *(float4*)&out[base] = o;
      }
    }
  }
}

extern "C" void kernel_launch(void* const* d_in, const int* in_sizes, int n_in,
                              void* d_out, int out_size, void* d_ws, size_t ws_size,
                              hipStream_t stream) {
  const float* x = (const float*)d_in[0];
  const int* src1 = (const int*)d_in[1];
  const int* dst1 = (const int*)d_in[2];
  const int* src2 = (const int*)d_in[3];
  const int* dst2 = (const int*)d_in[4];
  const float* W1 = (const float*)d_in[5];
  const float* al1 = (const float*)d_in[6];
  const float* ar1 = (const float*)d_in[7];
  const float* W2 = (const float*)d_in[8];
  const float* al2 = (const float*)d_in[9];
  const float* ar2 = (const float*)d_in[10];
  const float* g1 = (const float*)d_in[11];
  const float* b1 = (const float*)d_in[12];
  const float* g2 = (const float*)d_in[13];
  const float* b2 = (const float*)d_in[14];
  const float* fw1 = (const float*)d_in[15];
  const float* fb1 = (const float*)d_in[16];
  const float* fw2 = (const float*)d_in[17];
  const float* fb2 = (const float*)d_in[18];

  const int N = in_sizes[11];
  const int E1 = in_sizes[1];
  const int E2 = in_sizes[3];
  const int NT = N * kT;

  char* p = (char*)d_ws;
  auto alloc = [&](size_t bytes) -> char* {
    char* r = p;
    p += (bytes + 255) & ~(size_t)255;
    return r;
  };
  float* z1 = (float*)alloc((size_t)NT * 64 * 4);
  float* z2 = (float*)alloc((size_t)NT * 64 * 4);
  float* el1 = (float*)alloc((size_t)NT * 4 * 4);
  float* er1 = (float*)alloc((size_t)NT * 4 * 4);
  float* el2 = (float*)alloc((size_t)NT * 4 * 4);
  float* er2 = (float*)alloc((size_t)NT * 4 * 4);
  float* x2 = (float*)alloc((size_t)NT * 64 * 4);
  float* sc1 = (float*)alloc((size_t)N * 4);
  float* sh1 = (float*)alloc((size_t)N * 4);
  float* sc2 = (float*)alloc((size_t)N * 4);
  float* sh2 = (float*)alloc((size_t)N * 4);
  int* off1 = (int*)alloc((size_t)(N + 1) * 4);
  int* off2 = (int*)alloc((size_t)(N + 1) * 4);
  int* scsr1 = (int*)alloc((size_t)E1 * 4);
  int* scsr2 = (int*)alloc((size_t)E2 * 4);
  char* zero_base = p;
  int* deg1 = (int*)alloc((size_t)N * 4);
  int* cur1 = (int*)alloc((size_t)N * 4);
  int* deg2 = (int*)alloc((size_t)N * 4);
  int* cur2 = (int*)alloc((size_t)N * 4);
  float* bn2s = (float*)alloc((size_t)N * 4);
  float* bn2q = (float*)alloc((size_t)N * 4);
  size_t zero_bytes = (size_t)(p - zero_base);
  hipMemsetAsync(zero_base, 0, zero_bytes, stream);

  bn_stats_kernel<<<N, 256, 0, stream>>>(x, g1, b1, sc1, sh1, N);
  deg_kernel<<<(E1 + 255) / 256, 256, 0, stream>>>(dst1, deg1, E1);
  deg_kernel<<<(E2 + 255) / 256, 256, 0, stream>>>(dst2, deg2, E2);
  scan_kernel<<<1, 1024, 0, stream>>>(deg1, off1, N);
  scan_kernel<<<1, 1024, 0, stream>>>(deg2, off2, N);
  fill_kernel<<<(E1 + 255) / 256, 256, 0, stream>>>(src1, dst1, off1, cur1, scsr1, E1);
  fill_kernel<<<(E2 + 255) / 256, 256, 0, stream>>>(src2, dst2, off2, cur2, scsr2, E2);
  zel_kernel<<<1280, 256, 0, stream>>>(x, sc1, sh1, W1, al1, ar1, W2, al2, ar2, z1, z2, el1,
                                       er1, el2, er2, NT);
  agg_kernel<<<(NT + 3) / 4, 256, 0, stream>>>(x, scsr1, off1, el1, er1, z1, scsr2, off2, el2,
                                               er2, z2, x2, bn2s, bn2q, NT);
  bn2fin_kernel<<<(N + 255) / 256, 256, 0, stream>>>(bn2s, bn2q, g2, b2, sc2, sh2, N);
  ff_kernel<<<512, 256, 0, stream>>>(x2, sc2, sh2, fw1, fb1, fw2, fb2, (float*)d_out, NT);
}

// Round 4
// 377.128 us; speedup vs baseline: 5.4781x; 1.2010x over previous
//
#include <hip/hip_runtime.h>
#include <math.h>

constexpr int kT = 12;
constexpr float kNeg = 0.2f;
constexpr float kEps = 1e-5f;
constexpr float kLog2e = 1.44269504088896f;

typedef __attribute__((ext_vector_type(8))) short bf16x8;
typedef __attribute__((ext_vector_type(4))) float f32x4;

__device__ __forceinline__ short f2bf(float f) {
  union { float f; unsigned u; } v;
  v.f = f;
  return (short)((v.u + 0x7fffu + ((v.u >> 16) & 1u)) >> 16);
}
__device__ __forceinline__ unsigned pack2(float a, float b) {
  return (unsigned)(unsigned short)f2bf(a) | ((unsigned)(unsigned short)f2bf(b) << 16);
}
__device__ __forceinline__ float bf2f(unsigned short u) {
  return __uint_as_float(((unsigned)u) << 16);
}

__device__ __forceinline__ float wave_reduce_sum(float v) {
#pragma unroll
  for (int o = 32; o > 0; o >>= 1) v += __shfl_xor(v, o);
  return v;
}

// Per-node BN1 statistics folded into scale/shift: h = x*scale + shift
__global__ void bn_stats_kernel(const float* __restrict__ x, const float* __restrict__ g,
                                const float* __restrict__ b, float* __restrict__ scale,
                                float* __restrict__ shift, int N) {
  int n = blockIdx.x;
  const float* xr = x + (size_t)n * (kT * 64);
  float s = 0.f, s2 = 0.f;
  for (int i = threadIdx.x; i < kT * 64; i += blockDim.x) {
    float v = xr[i];
    s += v;
    s2 += v * v;
  }
  s = wave_reduce_sum(s);
  s2 = wave_reduce_sum(s2);
  __shared__ float ls[4], ls2[4];
  int wid = threadIdx.x >> 6, lane = threadIdx.x & 63;
  if (lane == 0) { ls[wid] = s; ls2[wid] = s2; }
  __syncthreads();
  if (threadIdx.x == 0) {
    float ts = 0.f, ts2 = 0.f;
    for (int i = 0; i < 4; i++) { ts += ls[i]; ts2 += ls2[i]; }
    const float inv = 1.f / (kT * 64);
    float mean = ts * inv;
    float var = ts2 * inv - mean * mean;
    float sc = rsqrtf(var + kEps) * g[n];
    scale[n] = sc;
    shift[n] = b[n] - mean * sc;
  }
}

// fused degree count for both relations
__global__ void deg_kernel(const int* __restrict__ dst1, const int* __restrict__ dst2,
                           int* __restrict__ deg1, int* __restrict__ deg2, int E1, int E2) {
  int i = blockIdx.x * blockDim.x + threadIdx.x;
  if (i < E1) atomicAdd(&deg1[dst1[i]], 1);
  else if (i < E1 + E2) atomicAdd(&deg2[dst2[i - E1]], 1);
}

// two single-block scans (blockIdx 0 -> rel1, 1 -> rel2), shfl wave-scans
__global__ void scan_kernel(const int* __restrict__ deg1, int* __restrict__ off1,
                            const int* __restrict__ deg2, int* __restrict__ off2, int N) {
  const int* deg = blockIdx.x ? deg2 : deg1;
  int* off = blockIdx.x ? off2 : off1;
  __shared__ int wsum[16];
  __shared__ int carry;
  int tid = threadIdx.x, lane = tid & 63, wv = tid >> 6;
  if (tid == 0) { carry = 0; off[0] = 0; }
  __syncthreads();
  for (int base = 0; base < N; base += 1024) {
    int i = base + tid;
    int incl = (i < N) ? deg[i] : 0;
#pragma unroll
    for (int o = 1; o < 64; o <<= 1) {
      int y = __shfl_up(incl, o);
      if (lane >= o) incl += y;
    }
    if (lane == 63) wsum[wv] = incl;
    __syncthreads();
    if (tid < 16) {
      int p = wsum[tid];
#pragma unroll
      for (int o = 1; o < 16; o <<= 1) {
        int y = __shfl_up(p, o);
        if (tid >= o) p += y;
      }
      wsum[tid] = p;
    }
    __syncthreads();
    int prefix = carry + (wv > 0 ? wsum[wv - 1] : 0);
    if (i < N) off[i + 1] = prefix + incl;
    int total = carry + wsum[15];
    __syncthreads();
    if (tid == 0) carry = total;
    __syncthreads();
  }
}

// fused CSR fill; stores src*kT (z-row base) to kill a mul in the agg hot loop
__global__ void fill_kernel(const int* __restrict__ src1, const int* __restrict__ dst1,
                            const int* __restrict__ off1, int* __restrict__ cur1,
                            int* __restrict__ scsr1, const int* __restrict__ src2,
                            const int* __restrict__ dst2, const int* __restrict__ off2,
                            int* __restrict__ cur2, int* __restrict__ scsr2, int E1, int E2) {
  int i = blockIdx.x * blockDim.x + threadIdx.x;
  if (i < E1) {
    int d = dst1[i];
    int p = atomicAdd(&cur1[d], 1);
    scsr1[off1[d] + p] = src1[i] * kT;
  } else if (i < E1 + E2) {
    int k = i - E1;
    int d = dst2[k];
    int p = atomicAdd(&cur2[d], 1);
    scsr2[off2[d] + p] = src2[k] * kT;
  }
}

// ---------------------------------------------------------------------------
// MFMA zel: 16 rows per wave-tile, z^T[64][16] = W^T @ h^T per relation.
// z stored bf16; el/er computed from fp32 acc via per-lane dot + q-group shfl,
// pre-scaled by log2(e) so agg's edge weight is a bare v_exp.
// ---------------------------------------------------------------------------
__global__ __launch_bounds__(256) void zel_kernel(
    const float* __restrict__ x, const float* __restrict__ scale,
    const float* __restrict__ shift, const float* __restrict__ W1,
    const float* __restrict__ al1, const float* __restrict__ ar1,
    const float* __restrict__ W2, const float* __restrict__ al2,
    const float* __restrict__ ar2, unsigned short* __restrict__ z1,
    unsigned short* __restrict__ z2, float* __restrict__ el1, float* __restrict__ er1,
    float* __restrict__ el2, float* __restrict__ er2, int NT) {
  __shared__ bf16x8 sW1[8][64];  // [mt*2+kc][lane]: W^T A-frags
  __shared__ bf16x8 sW2[8][64];
  int lane = threadIdx.x & 63, wid = threadIdx.x >> 6;
  int m = lane & 15, q = lane >> 4;
  for (int fi = wid; fi < 8; fi += 4) {
    int mt = fi >> 1, kc = fi & 1;
    bf16x8 v, u;
#pragma unroll
    for (int j = 0; j < 8; j++) {
      int d = kc * 32 + q * 8 + j;
      v[j] = f2bf(W1[d * 64 + mt * 16 + m]);
      u[j] = f2bf(W2[d * 64 + mt * 16 + m]);
    }
    sW1[fi][lane] = v;
    sW2[fi][lane] = u;
  }
  __syncthreads();
  float al1r[4][4], ar1r[4][4], al2r[4][4], ar2r[4][4];
#pragma unroll
  for (int h = 0; h < 4; h++)
#pragma unroll
    for (int r = 0; r < 4; r++) {
      int f = h * 16 + 4 * q + r;
      al1r[h][r] = al1[f] * kLog2e;
      ar1r[h][r] = ar1[f] * kLog2e;
      al2r[h][r] = al2[f] * kLog2e;
      ar2r[h][r] = ar2[f] * kLog2e;
    }
  int ntile = (NT + 15) / 16;
  for (int tile = blockIdx.x * 4 + wid; tile < ntile; tile += gridDim.x * 4) {
    int r0 = tile * 16;
    int row = r0 + m;
    int rowc = (row < NT) ? row : NT - 1;
    int n = rowc / kT;
    float sc = scale[n], sh = shift[n];
    bf16x8 hf[2];
#pragma unroll
    for (int kc = 0; kc < 2; kc++) {
      float4 p0 = *(const float4*)&x[(size_t)rowc * 64 + kc * 32 + q * 8];
      float4 p1 = *(const float4*)&x[(size_t)rowc * 64 + kc * 32 + q * 8 + 4];
      hf[kc][0] = f2bf(fmaf(p0.x, sc, sh));
      hf[kc][1] = f2bf(fmaf(p0.y, sc, sh));
      hf[kc][2] = f2bf(fmaf(p0.z, sc, sh));
      hf[kc][3] = f2bf(fmaf(p0.w, sc, sh));
      hf[kc][4] = f2bf(fmaf(p1.x, sc, sh));
      hf[kc][5] = f2bf(fmaf(p1.y, sc, sh));
      hf[kc][6] = f2bf(fmaf(p1.z, sc, sh));
      hf[kc][7] = f2bf(fmaf(p1.w, sc, sh));
    }
    f32x4 a1[4], a2[4];
#pragma unroll
    for (int mt = 0; mt < 4; mt++) {
      a1[mt] = (f32x4){0.f, 0.f, 0.f, 0.f};
      a2[mt] = (f32x4){0.f, 0.f, 0.f, 0.f};
    }
#pragma unroll
    for (int kc = 0; kc < 2; kc++)
#pragma unroll
      for (int mt = 0; mt < 4; mt++) {
        a1[mt] = __builtin_amdgcn_mfma_f32_16x16x32_bf16(sW1[mt * 2 + kc][lane], hf[kc],
                                                         a1[mt], 0, 0, 0);
        a2[mt] = __builtin_amdgcn_mfma_f32_16x16x32_bf16(sW2[mt * 2 + kc][lane], hf[kc],
                                                         a2[mt], 0, 0, 0);
      }
    // el/er: acc[h][r] = z[row=m][feat=h*16+4q+r]; reduce over q-groups
    float e1l[4], e1r[4], e2l[4], e2r[4];
#pragma unroll
    for (int h = 0; h < 4; h++) {
      float pl1 = 0.f, pr1 = 0.f, pl2 = 0.f, pr2 = 0.f;
#pragma unroll
      for (int r = 0; r < 4; r++) {
        pl1 = fmaf(a1[h][r], al1r[h][r], pl1);
        pr1 = fmaf(a1[h][r], ar1r[h][r], pr1);
        pl2 = fmaf(a2[h][r], al2r[h][r], pl2);
        pr2 = fmaf(a2[h][r], ar2r[h][r], pr2);
      }
#pragma unroll
      for (int o = 16; o < 64; o <<= 1) {
        pl1 += __shfl_xor(pl1, o);
        pr1 += __shfl_xor(pr1, o);
        pl2 += __shfl_xor(pl2, o);
        pr2 += __shfl_xor(pr2, o);
      }
      e1l[h] = pl1; e1r[h] = pr1; e2l[h] = pl2; e2r[h] = pr2;
    }
    if (row < NT) {
      if (q == 0) {
        *(float4*)&el1[(size_t)row * 4] = make_float4(e1l[0], e1l[1], e1l[2], e1l[3]);
        *(float4*)&er1[(size_t)row * 4] = make_float4(e1r[0], e1r[1], e1r[2], e1r[3]);
        *(float4*)&el2[(size_t)row * 4] = make_float4(e2l[0], e2l[1], e2l[2], e2l[3]);
        *(float4*)&er2[(size_t)row * 4] = make_float4(e2r[0], e2r[1], e2r[2], e2r[3]);
      }
#pragma unroll
      for (int mt = 0; mt < 4; mt++) {
        uint2 u1 = {pack2(a1[mt][0], a1[mt][1]), pack2(a1[mt][2], a1[mt][3])};
        uint2 u2 = {pack2(a2[mt][0], a2[mt][1]), pack2(a2[mt][2], a2[mt][3])};
        *(uint2*)&z1[(size_t)row * 64 + mt * 16 + 4 * q] = u1;
        *(uint2*)&z2[(size_t)row * 64 + mt * 16 + 4 * q] = u2;
      }
    }
  }
}

// Single-pass softmax gather; scsr holds s*kT, el/er pre-scaled by log2e.
__device__ __forceinline__ float gat_rel(int n, int t, int lane, int h,
                                         const int* __restrict__ scsr,
                                         const int* __restrict__ off,
                                         const float* __restrict__ el, float er_h,
                                         const unsigned short* __restrict__ z) {
  int b0 = off[n], b1 = off[n + 1];
  if (b1 <= b0) return 0.f;
  float num = 0.f, den = 0.f;
  int sb_next = scsr[b0];
#pragma unroll 2
  for (int j = b0; j < b1; j++) {
    int sb = sb_next;
    if (j + 1 < b1) sb_next = scsr[j + 1];
    int srow = sb + t;
    float ev = el[srow * 4 + h] + er_h;
    ev = ev < 0.f ? kNeg * ev : ev;
    float w = exp2f(ev);
    den += w;
    num = fmaf(w, bf2f(z[(size_t)srow * 64 + lane]), num);
  }
  return num / den;
}

__global__ void agg_kernel(const float* __restrict__ x, const int* __restrict__ scsr1,
                           const int* __restrict__ off1, const float* __restrict__ el1,
                           const float* __restrict__ er1, const unsigned short* __restrict__ z1,
                           const int* __restrict__ scsr2, const int* __restrict__ off2,
                           const float* __restrict__ el2, const float* __restrict__ er2,
                           const unsigned short* __restrict__ z2, float* __restrict__ x2,
                           float* __restrict__ bn2s, float* __restrict__ bn2q, int NT) {
  int wid = threadIdx.x >> 6, lane = threadIdx.x & 63;
  int row = blockIdx.x * 4 + wid;
  if (row >= NT) return;
  int n = row / kT;
  int t = row - n * kT;
  int h = lane >> 4;
  float acc = gat_rel(n, t, lane, h, scsr1, off1, el1, er1[(size_t)row * 4 + h], z1) +
              gat_rel(n, t, lane, h, scsr2, off2, el2, er2[(size_t)row * 4 + h], z2);
  float xv = x[(size_t)row * 64 + lane];
  float x2v = xv + acc;
  x2[(size_t)row * 64 + lane] = x2v;
  float s1 = wave_reduce_sum(x2v);
  float s2 = wave_reduce_sum(x2v * x2v);
  if (lane == 0) {
    atomicAdd(&bn2s[n], s1);
    atomicAdd(&bn2q[n], s2);
  }
}

// ---------------------------------------------------------------------------
// MFMA FF with BN2 finalize fused (reads raw bn2s/bn2q sums per node).
// ---------------------------------------------------------------------------
__global__ __launch_bounds__(256) void ff_kernel(
    const float* __restrict__ x2, const float* __restrict__ bn2s,
    const float* __restrict__ bn2q, const float* __restrict__ bng,
    const float* __restrict__ bnb, const float* __restrict__ w1,
    const float* __restrict__ b1, const float* __restrict__ w2,
    const float* __restrict__ b2, float* __restrict__ out, int NT) {
  __shared__ bf16x8 sW1[16][64];
  __shared__ bf16x8 sW2[16][64];
  int lane = threadIdx.x & 63, wid = threadIdx.x >> 6;
  int m = lane & 15, q = lane >> 4;

  for (int fi = wid; fi < 16; fi += 4) {
    int mt = fi >> 1, kc = fi & 1;
    bf16x8 v;
#pragma unroll
    for (int j = 0; j < 8; j++)
      v[j] = f2bf(w1[(kc * 32 + q * 8 + j) * 128 + mt * 16 + m]);
    sW1[fi][lane] = v;
    int mt2 = fi >> 2, kc2 = fi & 3;
    bf16x8 u;
#pragma unroll
    for (int j = 0; j < 8; j++)
      u[j] = f2bf(w2[(kc2 * 32 + q * 8 + j) * 64 + mt2 * 16 + m]);
    sW2[fi][lane] = u;
  }
  __syncthreads();

  float bias1v[8][4], bias2v[4][4];
#pragma unroll
  for (int mt = 0; mt < 8; mt++)
#pragma unroll
    for (int r = 0; r < 4; r++) bias1v[mt][r] = b1[mt * 16 + 4 * q + r];
#pragma unroll
  for (int mt = 0; mt < 4; mt++)
#pragma unroll
    for (int r = 0; r < 4; r++) bias2v[mt][r] = b2[mt * 16 + 4 * q + r];

  const float inv = 1.f / (kT * 64);
  int ntile = (NT + 15) / 16;
  for (int tile = blockIdx.x * 4 + wid; tile < ntile; tile += gridDim.x * 4) {
    int r0 = tile * 16;
    int row = r0 + m;
    int rowc = (row < NT) ? row : NT - 1;
    int n = rowc / kT;
    float mean = bn2s[n] * inv;
    float var = bn2q[n] * inv - mean * mean;
    float sc = rsqrtf(var + kEps) * bng[n];
    float sh = bnb[n] - mean * sc;

    bf16x8 hf[2];
#pragma unroll
    for (int kc = 0; kc < 2; kc++) {
      const float4 p0 = *(const float4*)&x2[(size_t)rowc * 64 + kc * 32 + q * 8];
      const float4 p1 = *(const float4*)&x2[(size_t)rowc * 64 + kc * 32 + q * 8 + 4];
      hf[kc][0] = f2bf(fmaf(p0.x, sc, sh));
      hf[kc][1] = f2bf(fmaf(p0.y, sc, sh));
      hf[kc][2] = f2bf(fmaf(p0.z, sc, sh));
      hf[kc][3] = f2bf(fmaf(p0.w, sc, sh));
      hf[kc][4] = f2bf(fmaf(p1.x, sc, sh));
      hf[kc][5] = f2bf(fmaf(p1.y, sc, sh));
      hf[kc][6] = f2bf(fmaf(p1.z, sc, sh));
      hf[kc][7] = f2bf(fmaf(p1.w, sc, sh));
    }

    f32x4 acc[8];
#pragma unroll
    for (int mt = 0; mt < 8; mt++) acc[mt] = (f32x4){0.f, 0.f, 0.f, 0.f};
#pragma unroll
    for (int kc = 0; kc < 2; kc++)
#pragma unroll
      for (int mt = 0; mt < 8; mt++)
        acc[mt] = __builtin_amdgcn_mfma_f32_16x16x32_bf16(sW1[mt * 2 + kc][lane], hf[kc],
                                                          acc[mt], 0, 0, 0);
    float g[8][4];
#pragma unroll
    for (int mt = 0; mt < 8; mt++)
#pragma unroll
      for (int r = 0; r < 4; r++) {
        float u = acc[mt][r] + bias1v[mt][r];
        g[mt][r] = 0.5f * u * (1.f + erff(u * 0.70710678118654752f));
      }

    bf16x8 b2f[4];
#pragma unroll
    for (int kc = 0; kc < 4; kc++)
#pragma unroll
      for (int j = 0; j < 8; j++) {
        int srcq = (2 * q + (j >> 2)) & 3;
        int src = srcq * 16 + m;
        float v0 = __shfl(g[2 * kc][j & 3], src);
        float v1 = __shfl(g[2 * kc + 1][j & 3], src);
        b2f[kc][j] = f2bf((q >= 2) ? v1 : v0);
      }

    f32x4 acc2[4];
#pragma unroll
    for (int mt = 0; mt < 4; mt++) acc2[mt] = (f32x4){0.f, 0.f, 0.f, 0.f};
#pragma unroll
    for (int kc = 0; kc < 4; kc++)
#pragma unroll
      for (int mt = 0; mt < 4; mt++)
        acc2[mt] = __builtin_amdgcn_mfma_f32_16x16x32_bf16(sW2[mt * 4 + kc][lane], b2f[kc],
                                                           acc2[mt], 0, 0, 0);

    if (row < NT) {
#pragma unroll
      for (int mt = 0; mt < 4; mt++) {
        size_t base = (size_t)row * 64 + mt * 16 + 4 * q;
        float4 xr = *(const float4*)&x2[base];
        float4 o;
        o.x = acc2[mt][0] + bias2v[mt][0] + xr.x;
        o.y = acc2[mt][1] + bias2v[mt][1] + xr.y;
        o.z = acc2[mt][2] + bias2v[mt][2] + xr.z;
        o.w = acc2[mt][3] + bias2v[mt][3] + xr.w;
        *(float4*)&out[base] = o;
      }
    }
  }
}

extern "C" void kernel_launch(void* const* d_in, const int* in_sizes, int n_in,
                              void* d_out, int out_size, void* d_ws, size_t ws_size,
                              hipStream_t stream) {
  const float* x = (const float*)d_in[0];
  const int* src1 = (const int*)d_in[1];
  const int* dst1 = (const int*)d_in[2];
  const int* src2 = (const int*)d_in[3];
  const int* dst2 = (const int*)d_in[4];
  const float* W1 = (const float*)d_in[5];
  const float* al1 = (const float*)d_in[6];
  const float* ar1 = (const float*)d_in[7];
  const float* W2 = (const float*)d_in[8];
  const float* al2 = (const float*)d_in[9];
  const float* ar2 = (const float*)d_in[10];
  const float* g1 = (const float*)d_in[11];
  const float* b1 = (const float*)d_in[12];
  const float* g2 = (const float*)d_in[13];
  const float* b2 = (const float*)d_in[14];
  const float* fw1 = (const float*)d_in[15];
  const float* fb1 = (const float*)d_in[16];
  const float* fw2 = (const float*)d_in[17];
  const float* fb2 = (const float*)d_in[18];

  const int N = in_sizes[11];
  const int E1 = in_sizes[1];
  const int E2 = in_sizes[3];
  const int NT = N * kT;

  char* p = (char*)d_ws;
  auto alloc = [&](size_t bytes) -> char* {
    char* r = p;
    p += (bytes + 255) & ~(size_t)255;
    return r;
  };
  unsigned short* z1 = (unsigned short*)alloc((size_t)NT * 64 * 2);
  unsigned short* z2 = (unsigned short*)alloc((size_t)NT * 64 * 2);
  float* el1 = (float*)alloc((size_t)NT * 4 * 4);
  float* er1 = (float*)alloc((size_t)NT * 4 * 4);
  float* el2 = (float*)alloc((size_t)NT * 4 * 4);
  float* er2 = (float*)alloc((size_t)NT * 4 * 4);
  float* x2 = (float*)alloc((size_t)NT * 64 * 4);
  float* sc1 = (float*)alloc((size_t)N * 4);
  float* sh1 = (float*)alloc((size_t)N * 4);
  int* off1 = (int*)alloc((size_t)(N + 1) * 4);
  int* off2 = (int*)alloc((size_t)(N + 1) * 4);
  int* scsr1 = (int*)alloc((size_t)E1 * 4);
  int* scsr2 = (int*)alloc((size_t)E2 * 4);
  char* zero_base = p;
  int* deg1 = (int*)alloc((size_t)N * 4);
  int* cur1 = (int*)alloc((size_t)N * 4);
  int* deg2 = (int*)alloc((size_t)N * 4);
  int* cur2 = (int*)alloc((size_t)N * 4);
  float* bn2s = (float*)alloc((size_t)N * 4);
  float* bn2q = (float*)alloc((size_t)N * 4);
  size_t zero_bytes = (size_t)(p - zero_base);
  hipMemsetAsync(zero_base, 0, zero_bytes, stream);

  bn_stats_kernel<<<N, 256, 0, stream>>>(x, g1, b1, sc1, sh1, N);
  deg_kernel<<<(E1 + E2 + 255) / 256, 256, 0, stream>>>(dst1, dst2, deg1, deg2, E1, E2);
  scan_kernel<<<2, 1024, 0, stream>>>(deg1, off1, deg2, off2, N);
  fill_kernel<<<(E1 + E2 + 255) / 256, 256, 0, stream>>>(src1, dst1, off1, cur1, scsr1, src2,
                                                         dst2, off2, cur2, scsr2, E1, E2);
  zel_kernel<<<1875, 256, 0, stream>>>(x, sc1, sh1, W1, al1, ar1, W2, al2, ar2, z1, z2, el1,
                                       er1, el2, er2, NT);
  agg_kernel<<<(NT + 3) / 4, 256, 0, stream>>>(x, scsr1, off1, el1, er1, z1, scsr2, off2, el2,
                                               er2, z2, x2, bn2s, bn2q, NT);
  ff_kernel<<<512, 256, 0, stream>>>(x2, bn2s, bn2q, g2, b2, fw1, fb1, fw2, fb2,
                                     (float*)d_out, NT);
}

// Round 5
// 287.561 us; speedup vs baseline: 7.1844x; 1.3115x over previous
//
#include <hip/hip_runtime.h>
#include <math.h>

constexpr int kT = 12;
constexpr float kNeg = 0.2f;
constexpr float kEps = 1e-5f;
constexpr float kLog2e = 1.44269504088896f;

typedef __attribute__((ext_vector_type(8))) short bf16x8;
typedef __attribute__((ext_vector_type(4))) float f32x4;

__device__ __forceinline__ short f2bf(float f) {
  union { float f; unsigned u; } v;
  v.f = f;
  return (short)((v.u + 0x7fffu + ((v.u >> 16) & 1u)) >> 16);
}
__device__ __forceinline__ unsigned pack2(float a, float b) {
  return (unsigned)(unsigned short)f2bf(a) | ((unsigned)(unsigned short)f2bf(b) << 16);
}

__device__ __forceinline__ float wave_reduce_sum(float v) {
#pragma unroll
  for (int o = 32; o > 0; o >>= 1) v += __shfl_xor(v, o);
  return v;
}

// Per-node BN1 statistics folded into scale/shift: h = x*scale + shift
__global__ void bn_stats_kernel(const float* __restrict__ x, const float* __restrict__ g,
                                const float* __restrict__ b, float* __restrict__ scale,
                                float* __restrict__ shift, int N) {
  int n = blockIdx.x;
  const float* xr = x + (size_t)n * (kT * 64);
  float s = 0.f, s2 = 0.f;
  for (int i = threadIdx.x; i < kT * 64; i += blockDim.x) {
    float v = xr[i];
    s += v;
    s2 += v * v;
  }
  s = wave_reduce_sum(s);
  s2 = wave_reduce_sum(s2);
  __shared__ float ls[4], ls2[4];
  int wid = threadIdx.x >> 6, lane = threadIdx.x & 63;
  if (lane == 0) { ls[wid] = s; ls2[wid] = s2; }
  __syncthreads();
  if (threadIdx.x == 0) {
    float ts = 0.f, ts2 = 0.f;
    for (int i = 0; i < 4; i++) { ts += ls[i]; ts2 += ls2[i]; }
    const float inv = 1.f / (kT * 64);
    float mean = ts * inv;
    float var = ts2 * inv - mean * mean;
    float sc = rsqrtf(var + kEps) * g[n];
    scale[n] = sc;
    shift[n] = b[n] - mean * sc;
  }
}

// fused degree count for both relations
__global__ void deg_kernel(const int* __restrict__ dst1, const int* __restrict__ dst2,
                           int* __restrict__ deg1, int* __restrict__ deg2, int E1, int E2) {
  int i = blockIdx.x * blockDim.x + threadIdx.x;
  if (i < E1) atomicAdd(&deg1[dst1[i]], 1);
  else if (i < E1 + E2) atomicAdd(&deg2[dst2[i - E1]], 1);
}

// two single-block scans (blockIdx 0 -> rel1, 1 -> rel2), shfl wave-scans
__global__ void scan_kernel(const int* __restrict__ deg1, int* __restrict__ off1,
                            const int* __restrict__ deg2, int* __restrict__ off2, int N) {
  const int* deg = blockIdx.x ? deg2 : deg1;
  int* off = blockIdx.x ? off2 : off1;
  __shared__ int wsum[16];
  __shared__ int carry;
  int tid = threadIdx.x, lane = tid & 63, wv = tid >> 6;
  if (tid == 0) { carry = 0; off[0] = 0; }
  __syncthreads();
  for (int base = 0; base < N; base += 1024) {
    int i = base + tid;
    int incl = (i < N) ? deg[i] : 0;
#pragma unroll
    for (int o = 1; o < 64; o <<= 1) {
      int y = __shfl_up(incl, o);
      if (lane >= o) incl += y;
    }
    if (lane == 63) wsum[wv] = incl;
    __syncthreads();
    if (tid < 16) {
      int p = wsum[tid];
#pragma unroll
      for (int o = 1; o < 16; o <<= 1) {
        int y = __shfl_up(p, o);
        if (tid >= o) p += y;
      }
      wsum[tid] = p;
    }
    __syncthreads();
    int prefix = carry + (wv > 0 ? wsum[wv - 1] : 0);
    if (i < N) off[i + 1] = prefix + incl;
    int total = carry + wsum[15];
    __syncthreads();
    if (tid == 0) carry = total;
    __syncthreads();
  }
}

// fused CSR fill; stores src*kT (z-row base) to kill a mul in the agg hot loop
__global__ void fill_kernel(const int* __restrict__ src1, const int* __restrict__ dst1,
                            const int* __restrict__ off1, int* __restrict__ cur1,
                            int* __restrict__ scsr1, const int* __restrict__ src2,
                            const int* __restrict__ dst2, const int* __restrict__ off2,
                            int* __restrict__ cur2, int* __restrict__ scsr2, int E1, int E2) {
  int i = blockIdx.x * blockDim.x + threadIdx.x;
  if (i < E1) {
    int d = dst1[i];
    int p = atomicAdd(&cur1[d], 1);
    scsr1[off1[d] + p] = src1[i] * kT;
  } else if (i < E1 + E2) {
    int k = i - E1;
    int d = dst2[k];
    int p = atomicAdd(&cur2[d], 1);
    scsr2[off2[d] + p] = src2[k] * kT;
  }
}

// ---------------------------------------------------------------------------
// MFMA zel: 16 rows per wave-tile, z^T[64][16] = W^T @ h^T per relation.
// z stored bf16; el/er pre-scaled by log2(e) so agg uses a bare v_exp.
// ---------------------------------------------------------------------------
__global__ __launch_bounds__(256) void zel_kernel(
    const float* __restrict__ x, const float* __restrict__ scale,
    const float* __restrict__ shift, const float* __restrict__ W1,
    const float* __restrict__ al1, const float* __restrict__ ar1,
    const float* __restrict__ W2, const float* __restrict__ al2,
    const float* __restrict__ ar2, unsigned short* __restrict__ z1,
    unsigned short* __restrict__ z2, float* __restrict__ el1, float* __restrict__ er1,
    float* __restrict__ el2, float* __restrict__ er2, int NT) {
  __shared__ bf16x8 sW1[8][64];
  __shared__ bf16x8 sW2[8][64];
  int lane = threadIdx.x & 63, wid = threadIdx.x >> 6;
  int m = lane & 15, q = lane >> 4;
  for (int fi = wid; fi < 8; fi += 4) {
    int mt = fi >> 1, kc = fi & 1;
    bf16x8 v, u;
#pragma unroll
    for (int j = 0; j < 8; j++) {
      int d = kc * 32 + q * 8 + j;
      v[j] = f2bf(W1[d * 64 + mt * 16 + m]);
      u[j] = f2bf(W2[d * 64 + mt * 16 + m]);
    }
    sW1[fi][lane] = v;
    sW2[fi][lane] = u;
  }
  __syncthreads();
  float al1r[4][4], ar1r[4][4], al2r[4][4], ar2r[4][4];
#pragma unroll
  for (int h = 0; h < 4; h++)
#pragma unroll
    for (int r = 0; r < 4; r++) {
      int f = h * 16 + 4 * q + r;
      al1r[h][r] = al1[f] * kLog2e;
      ar1r[h][r] = ar1[f] * kLog2e;
      al2r[h][r] = al2[f] * kLog2e;
      ar2r[h][r] = ar2[f] * kLog2e;
    }
  int ntile = (NT + 15) / 16;
  for (int tile = blockIdx.x * 4 + wid; tile < ntile; tile += gridDim.x * 4) {
    int r0 = tile * 16;
    int row = r0 + m;
    int rowc = (row < NT) ? row : NT - 1;
    int n = rowc / kT;
    float sc = scale[n], sh = shift[n];
    bf16x8 hf[2];
#pragma unroll
    for (int kc = 0; kc < 2; kc++) {
      float4 p0 = *(const float4*)&x[(size_t)rowc * 64 + kc * 32 + q * 8];
      float4 p1 = *(const float4*)&x[(size_t)rowc * 64 + kc * 32 + q * 8 + 4];
      hf[kc][0] = f2bf(fmaf(p0.x, sc, sh));
      hf[kc][1] = f2bf(fmaf(p0.y, sc, sh));
      hf[kc][2] = f2bf(fmaf(p0.z, sc, sh));
      hf[kc][3] = f2bf(fmaf(p0.w, sc, sh));
      hf[kc][4] = f2bf(fmaf(p1.x, sc, sh));
      hf[kc][5] = f2bf(fmaf(p1.y, sc, sh));
      hf[kc][6] = f2bf(fmaf(p1.z, sc, sh));
      hf[kc][7] = f2bf(fmaf(p1.w, sc, sh));
    }
    f32x4 a1[4], a2[4];
#pragma unroll
    for (int mt = 0; mt < 4; mt++) {
      a1[mt] = (f32x4){0.f, 0.f, 0.f, 0.f};
      a2[mt] = (f32x4){0.f, 0.f, 0.f, 0.f};
    }
#pragma unroll
    for (int kc = 0; kc < 2; kc++)
#pragma unroll
      for (int mt = 0; mt < 4; mt++) {
        a1[mt] = __builtin_amdgcn_mfma_f32_16x16x32_bf16(sW1[mt * 2 + kc][lane], hf[kc],
                                                         a1[mt], 0, 0, 0);
        a2[mt] = __builtin_amdgcn_mfma_f32_16x16x32_bf16(sW2[mt * 2 + kc][lane], hf[kc],
                                                         a2[mt], 0, 0, 0);
      }
    float e1l[4], e1r[4], e2l[4], e2r[4];
#pragma unroll
    for (int h = 0; h < 4; h++) {
      float pl1 = 0.f, pr1 = 0.f, pl2 = 0.f, pr2 = 0.f;
#pragma unroll
      for (int r = 0; r < 4; r++) {
        pl1 = fmaf(a1[h][r], al1r[h][r], pl1);
        pr1 = fmaf(a1[h][r], ar1r[h][r], pr1);
        pl2 = fmaf(a2[h][r], al2r[h][r], pl2);
        pr2 = fmaf(a2[h][r], ar2r[h][r], pr2);
      }
#pragma unroll
      for (int o = 16; o < 64; o <<= 1) {
        pl1 += __shfl_xor(pl1, o);
        pr1 += __shfl_xor(pr1, o);
        pl2 += __shfl_xor(pl2, o);
        pr2 += __shfl_xor(pr2, o);
      }
      e1l[h] = pl1; e1r[h] = pr1; e2l[h] = pl2; e2r[h] = pr2;
    }
    if (row < NT) {
      if (q == 0) {
        *(float4*)&el1[(size_t)row * 4] = make_float4(e1l[0], e1l[1], e1l[2], e1l[3]);
        *(float4*)&er1[(size_t)row * 4] = make_float4(e1r[0], e1r[1], e1r[2], e1r[3]);
        *(float4*)&el2[(size_t)row * 4] = make_float4(e2l[0], e2l[1], e2l[2], e2l[3]);
        *(float4*)&er2[(size_t)row * 4] = make_float4(e2r[0], e2r[1], e2r[2], e2r[3]);
      }
#pragma unroll
      for (int mt = 0; mt < 4; mt++) {
        uint2 u1 = {pack2(a1[mt][0], a1[mt][1]), pack2(a1[mt][2], a1[mt][3])};
        uint2 u2 = {pack2(a2[mt][0], a2[mt][1]), pack2(a2[mt][2], a2[mt][3])};
        *(uint2*)&z1[(size_t)row * 64 + mt * 16 + 4 * q] = u1;
        *(uint2*)&z2[(size_t)row * 64 + mt * 16 + 4 * q] = u2;
      }
    }
  }
}

// ---------------------------------------------------------------------------
// agg v2: one wave per (node, t-block of 4). lane = (tl, cg): row n*12+t0+tl,
// channels cg*4..+3. Per edge iteration the wave covers 4 (edge,t) pairs:
// scsr/loop overhead amortized 4x, z read as uint2 (contiguous 512 B/wave),
// bf16 unpack hi=v_and lo=v_lshl, leaky = max(ev, 0.2*ev).
// ---------------------------------------------------------------------------
__global__ __launch_bounds__(256) void agg_kernel(
    const float* __restrict__ x, const int* __restrict__ scsr1,
    const int* __restrict__ off1, const float* __restrict__ el1,
    const float* __restrict__ er1, const unsigned short* __restrict__ z1,
    const int* __restrict__ scsr2, const int* __restrict__ off2,
    const float* __restrict__ el2, const float* __restrict__ er2,
    const unsigned short* __restrict__ z2, float* __restrict__ x2,
    float* __restrict__ bn2s, float* __restrict__ bn2q, int N) {
  int wid = threadIdx.x >> 6, lane = threadIdx.x & 63;
  int w = blockIdx.x * 4 + wid;
  if (w >= N * 3) return;
  int n = w / 3;
  int t0 = (w - n * 3) * 4;
  int tl = lane >> 4, cg = lane & 15;
  int t = t0 + tl;
  int row = n * kT + t;
  int h = cg >> 2;
  float a0 = 0.f, a1 = 0.f, a2 = 0.f, a3 = 0.f;

  {
    int b0 = off1[n], b1 = off1[n + 1];
    if (b1 > b0) {
      float er_h = er1[(size_t)row * 4 + h];
      const float* elp = el1 + h;
      const unsigned short* zp = z1 + cg * 4;
      float den = 0.f, n0 = 0.f, n1 = 0.f, n2 = 0.f, n3 = 0.f;
      int sb_next = scsr1[b0];
      for (int j = b0; j < b1; j++) {
        int sb = sb_next;
        if (j + 1 < b1) sb_next = scsr1[j + 1];
        int srow = sb + t;
        float ev = elp[(size_t)srow * 4] + er_h;
        ev = fmaxf(ev, kNeg * ev);
        float wgt = exp2f(ev);
        den += wgt;
        uint2 zv = *(const uint2*)(zp + (size_t)srow * 64);
        n0 = fmaf(wgt, __uint_as_float(zv.x << 16), n0);
        n1 = fmaf(wgt, __uint_as_float(zv.x & 0xffff0000u), n1);
        n2 = fmaf(wgt, __uint_as_float(zv.y << 16), n2);
        n3 = fmaf(wgt, __uint_as_float(zv.y & 0xffff0000u), n3);
      }
      float inv = 1.f / den;
      a0 = fmaf(n0, inv, a0);
      a1 = fmaf(n1, inv, a1);
      a2 = fmaf(n2, inv, a2);
      a3 = fmaf(n3, inv, a3);
    }
  }
  {
    int b0 = off2[n], b1 = off2[n + 1];
    if (b1 > b0) {
      float er_h = er2[(size_t)row * 4 + h];
      const float* elp = el2 + h;
      const unsigned short* zp = z2 + cg * 4;
      float den = 0.f, n0 = 0.f, n1 = 0.f, n2 = 0.f, n3 = 0.f;
      int sb_next = scsr2[b0];
      for (int j = b0; j < b1; j++) {
        int sb = sb_next;
        if (j + 1 < b1) sb_next = scsr2[j + 1];
        int srow = sb + t;
        float ev = elp[(size_t)srow * 4] + er_h;
        ev = fmaxf(ev, kNeg * ev);
        float wgt = exp2f(ev);
        den += wgt;
        uint2 zv = *(const uint2*)(zp + (size_t)srow * 64);
        n0 = fmaf(wgt, __uint_as_float(zv.x << 16), n0);
        n1 = fmaf(wgt, __uint_as_float(zv.x & 0xffff0000u), n1);
        n2 = fmaf(wgt, __uint_as_float(zv.y << 16), n2);
        n3 = fmaf(wgt, __uint_as_float(zv.y & 0xffff0000u), n3);
      }
      float inv = 1.f / den;
      a0 = fmaf(n0, inv, a0);
      a1 = fmaf(n1, inv, a1);
      a2 = fmaf(n2, inv, a2);
      a3 = fmaf(n3, inv, a3);
    }
  }

  size_t base = (size_t)row * 64 + cg * 4;
  float4 xr = *(const float4*)&x[base];
  float4 o;
  o.x = xr.x + a0;
  o.y = xr.y + a1;
  o.z = xr.z + a2;
  o.w = xr.w + a3;
  *(float4*)&x2[base] = o;
  float s1 = o.x + o.y + o.z + o.w;
  float s2 = o.x * o.x + o.y * o.y + o.z * o.z + o.w * o.w;
  s1 = wave_reduce_sum(s1);
  s2 = wave_reduce_sum(s2);
  if (lane == 0) {
    atomicAdd(&bn2s[n], s1);
    atomicAdd(&bn2q[n], s2);
  }
}

// ---------------------------------------------------------------------------
// MFMA FF with BN2 finalize fused (reads raw bn2s/bn2q sums per node).
// ---------------------------------------------------------------------------
__global__ __launch_bounds__(256) void ff_kernel(
    const float* __restrict__ x2, const float* __restrict__ bn2s,
    const float* __restrict__ bn2q, const float* __restrict__ bng,
    const float* __restrict__ bnb, const float* __restrict__ w1,
    const float* __restrict__ b1, const float* __restrict__ w2,
    const float* __restrict__ b2, float* __restrict__ out, int NT) {
  __shared__ bf16x8 sW1[16][64];
  __shared__ bf16x8 sW2[16][64];
  int lane = threadIdx.x & 63, wid = threadIdx.x >> 6;
  int m = lane & 15, q = lane >> 4;

  for (int fi = wid; fi < 16; fi += 4) {
    int mt = fi >> 1, kc = fi & 1;
    bf16x8 v;
#pragma unroll
    for (int j = 0; j < 8; j++)
      v[j] = f2bf(w1[(kc * 32 + q * 8 + j) * 128 + mt * 16 + m]);
    sW1[fi][lane] = v;
    int mt2 = fi >> 2, kc2 = fi & 3;
    bf16x8 u;
#pragma unroll
    for (int j = 0; j < 8; j++)
      u[j] = f2bf(w2[(kc2 * 32 + q * 8 + j) * 64 + mt2 * 16 + m]);
    sW2[fi][lane] = u;
  }
  __syncthreads();

  float bias1v[8][4], bias2v[4][4];
#pragma unroll
  for (int mt = 0; mt < 8; mt++)
#pragma unroll
    for (int r = 0; r < 4; r++) bias1v[mt][r] = b1[mt * 16 + 4 * q + r];
#pragma unroll
  for (int mt = 0; mt < 4; mt++)
#pragma unroll
    for (int r = 0; r < 4; r++) bias2v[mt][r] = b2[mt * 16 + 4 * q + r];

  const float inv = 1.f / (kT * 64);
  int ntile = (NT + 15) / 16;
  for (int tile = blockIdx.x * 4 + wid; tile < ntile; tile += gridDim.x * 4) {
    int r0 = tile * 16;
    int row = r0 + m;
    int rowc = (row < NT) ? row : NT - 1;
    int n = rowc / kT;
    float mean = bn2s[n] * inv;
    float var = bn2q[n] * inv - mean * mean;
    float sc = rsqrtf(var + kEps) * bng[n];
    float sh = bnb[n] - mean * sc;

    bf16x8 hf[2];
#pragma unroll
    for (int kc = 0; kc < 2; kc++) {
      const float4 p0 = *(const float4*)&x2[(size_t)rowc * 64 + kc * 32 + q * 8];
      const float4 p1 = *(const float4*)&x2[(size_t)rowc * 64 + kc * 32 + q * 8 + 4];
      hf[kc][0] = f2bf(fmaf(p0.x, sc, sh));
      hf[kc][1] = f2bf(fmaf(p0.y, sc, sh));
      hf[kc][2] = f2bf(fmaf(p0.z, sc, sh));
      hf[kc][3] = f2bf(fmaf(p0.w, sc, sh));
      hf[kc][4] = f2bf(fmaf(p1.x, sc, sh));
      hf[kc][5] = f2bf(fmaf(p1.y, sc, sh));
      hf[kc][6] = f2bf(fmaf(p1.z, sc, sh));
      hf[kc][7] = f2bf(fmaf(p1.w, sc, sh));
    }

    f32x4 acc[8];
#pragma unroll
    for (int mt = 0; mt < 8; mt++) acc[mt] = (f32x4){0.f, 0.f, 0.f, 0.f};
#pragma unroll
    for (int kc = 0; kc < 2; kc++)
#pragma unroll
      for (int mt = 0; mt < 8; mt++)
        acc[mt] = __builtin_amdgcn_mfma_f32_16x16x32_bf16(sW1[mt * 2 + kc][lane], hf[kc],
                                                          acc[mt], 0, 0, 0);
    float g[8][4];
#pragma unroll
    for (int mt = 0; mt < 8; mt++)
#pragma unroll
      for (int r = 0; r < 4; r++) {
        float u = acc[mt][r] + bias1v[mt][r];
        g[mt][r] = 0.5f * u * (1.f + erff(u * 0.70710678118654752f));
      }

    bf16x8 b2f[4];
#pragma unroll
    for (int kc = 0; kc < 4; kc++)
#pragma unroll
      for (int j = 0; j < 8; j++) {
        int srcq = (2 * q + (j >> 2)) & 3;
        int src = srcq * 16 + m;
        float v0 = __shfl(g[2 * kc][j & 3], src);
        float v1 = __shfl(g[2 * kc + 1][j & 3], src);
        b2f[kc][j] = f2bf((q >= 2) ? v1 : v0);
      }

    f32x4 acc2[4];
#pragma unroll
    for (int mt = 0; mt < 4; mt++) acc2[mt] = (f32x4){0.f, 0.f, 0.f, 0.f};
#pragma unroll
    for (int kc = 0; kc < 4; kc++)
#pragma unroll
      for (int mt = 0; mt < 4; mt++)
        acc2[mt] = __builtin_amdgcn_mfma_f32_16x16x32_bf16(sW2[mt * 4 + kc][lane], b2f[kc],
                                                           acc2[mt], 0, 0, 0);

    if (row < NT) {
#pragma unroll
      for (int mt = 0; mt < 4; mt++) {
        size_t base = (size_t)row * 64 + mt * 16 + 4 * q;
        float4 xr = *(const float4*)&x2[base];
        float4 o;
        o.x = acc2[mt][0] + bias2v[mt][0] + xr.x;
        o.y = acc2[mt][1] + bias2v[mt][1] + xr.y;
        o.z = acc2[mt][2] + bias2v[mt][2] + xr.z;
        o.w = acc2[mt][3] + bias2v[mt][3] + xr.w;
        *(float4*)&out[base] = o;
      }
    }
  }
}

extern "C" void kernel_launch(void* const* d_in, const int* in_sizes, int n_in,
                              void* d_out, int out_size, void* d_ws, size_t ws_size,
                              hipStream_t stream) {
  const float* x = (const float*)d_in[0];
  const int* src1 = (const int*)d_in[1];
  const int* dst1 = (const int*)d_in[2];
  const int* src2 = (const int*)d_in[3];
  const int* dst2 = (const int*)d_in[4];
  const float* W1 = (const float*)d_in[5];
  const float* al1 = (const float*)d_in[6];
  const float* ar1 = (const float*)d_in[7];
  const float* W2 = (const float*)d_in[8];
  const float* al2 = (const float*)d_in[9];
  const float* ar2 = (const float*)d_in[10];
  const float* g1 = (const float*)d_in[11];
  const float* b1 = (const float*)d_in[12];
  const float* g2 = (const float*)d_in[13];
  const float* b2 = (const float*)d_in[14];
  const float* fw1 = (const float*)d_in[15];
  const float* fb1 = (const float*)d_in[16];
  const float* fw2 = (const float*)d_in[17];
  const float* fb2 = (const float*)d_in[18];

  const int N = in_sizes[11];
  const int E1 = in_sizes[1];
  const int E2 = in_sizes[3];
  const int NT = N * kT;

  char* p = (char*)d_ws;
  auto alloc = [&](size_t bytes) -> char* {
    char* r = p;
    p += (bytes + 255) & ~(size_t)255;
    return r;
  };
  unsigned short* z1 = (unsigned short*)alloc((size_t)NT * 64 * 2);
  unsigned short* z2 = (unsigned short*)alloc((size_t)NT * 64 * 2);
  float* el1 = (float*)alloc((size_t)NT * 4 * 4);
  float* er1 = (float*)alloc((size_t)NT * 4 * 4);
  float* el2 = (float*)alloc((size_t)NT * 4 * 4);
  float* er2 = (float*)alloc((size_t)NT * 4 * 4);
  float* x2 = (float*)alloc((size_t)NT * 64 * 4);
  float* sc1 = (float*)alloc((size_t)N * 4);
  float* sh1 = (float*)alloc((size_t)N * 4);
  int* off1 = (int*)alloc((size_t)(N + 1) * 4);
  int* off2 = (int*)alloc((size_t)(N + 1) * 4);
  int* scsr1 = (int*)alloc((size_t)E1 * 4);
  int* scsr2 = (int*)alloc((size_t)E2 * 4);
  char* zero_base = p;
  int* deg1 = (int*)alloc((size_t)N * 4);
  int* cur1 = (int*)alloc((size_t)N * 4);
  int* deg2 = (int*)alloc((size_t)N * 4);
  int* cur2 = (int*)alloc((size_t)N * 4);
  float* bn2s = (float*)alloc((size_t)N * 4);
  float* bn2q = (float*)alloc((size_t)N * 4);
  size_t zero_bytes = (size_t)(p - zero_base);
  hipMemsetAsync(zero_base, 0, zero_bytes, stream);

  bn_stats_kernel<<<N, 256, 0, stream>>>(x, g1, b1, sc1, sh1, N);
  deg_kernel<<<(E1 + E2 + 255) / 256, 256, 0, stream>>>(dst1, dst2, deg1, deg2, E1, E2);
  scan_kernel<<<2, 1024, 0, stream>>>(deg1, off1, deg2, off2, N);
  fill_kernel<<<(E1 + E2 + 255) / 256, 256, 0, stream>>>(src1, dst1, off1, cur1, scsr1, src2,
                                                         dst2, off2, cur2, scsr2, E1, E2);
  zel_kernel<<<1875, 256, 0, stream>>>(x, sc1, sh1, W1, al1, ar1, W2, al2, ar2, z1, z2, el1,
                                       er1, el2, er2, NT);
  agg_kernel<<<(N * 3 + 3) / 4, 256, 0, stream>>>(x, scsr1, off1, el1, er1, z1, scsr2, off2,
                                                  el2, er2, z2, x2, bn2s, bn2q, N);
  ff_kernel<<<1024, 256, 0, stream>>>(x2, bn2s, bn2q, g2, b2, fw1, fb1, fw2, fb2,
                                      (float*)d_out, NT);
}